// Round 3
// baseline (962.546 us; speedup 1.0000x reference)
//
#include <hip/hip_runtime.h>

// ---------------------------------------------------------------------------
// AdaptiveTemporalAttention — MI355X gfx950
// B=4, S=2048, D=512, H=8, hd=64.
// Outputs: out (B,S,D) f32 then attn (B,H,S,S) f32, concatenated in d_out.
//
// Round 3: k_attn occupancy fix. 512-thread blocks: 8 waves = 4 row-groups
// x 2 j-halves -> 8192 waves = 32 waves/CU (needs VGPR<=64, forced via
// __launch_bounds__(512,8); round-1 code was 64 naturally). Rowsum combined
// across j-halves via LDS; PV partials combined via LDS at end. ts/mask
// staged in LDS. Softmax scale folded into Q GEMM. XCD swizzle kept.
// ---------------------------------------------------------------------------

#define S_LEN  2048
#define DM     512
#define NH     8
#define HDIM   64
#define BATCH  4
#define BHN    32     // BATCH*NH
#define BSROWS 8192   // BATCH*S_LEN

typedef __attribute__((ext_vector_type(8))) short short8v;
typedef __attribute__((ext_vector_type(8))) unsigned short ushort8v;
typedef __attribute__((ext_vector_type(4))) float f32x4;

static __device__ __forceinline__ unsigned short bf16_rne(float f){
  unsigned int u = __float_as_uint(f);
  u = (u + 0x7FFFu + ((u >> 16) & 1u)) >> 16;
  return (unsigned short)u;
}
static __device__ __forceinline__ float bf16_f32(unsigned short h){
  return __uint_as_float(((unsigned int)h) << 16);
}
static __device__ __forceinline__ f32x4 mfma16(short8v a, short8v b, f32x4 c){
  return __builtin_amdgcn_mfma_f32_16x16x32_bf16(a, b, c, 0, 0, 0);
}

// ---------------- prep: elementwise split f32 -> (hi,lo) bf16 ----------------
__global__ void k_split(const float* __restrict__ src,
                        unsigned short* __restrict__ hi,
                        unsigned short* __restrict__ lo, int n){
  for (int i = blockIdx.x*blockDim.x + threadIdx.x; i < n;
       i += gridDim.x*blockDim.x){
    float f = src[i];
    unsigned short h = bf16_rne(f);
    hi[i] = h;
    lo[i] = bf16_rne(f - bf16_f32(h));
  }
}

// ---------------- prep: transpose 512x512 W -> WT, split ----------------
__global__ void k_wsplit(const float* __restrict__ W,
                         unsigned short* __restrict__ Thi,
                         unsigned short* __restrict__ Tlo){
  int idx = blockIdx.x*blockDim.x + threadIdx.x; // (n,k) with k fastest
  int n = idx >> 9, k = idx & 511;
  float f = W[k*DM + n];
  unsigned short h = bf16_rne(f);
  Thi[idx] = h;
  Tlo[idx] = bf16_rne(f - bf16_f32(h));
}

// ---------------- split-precision GEMM: C = (A@B + bias)*cscale ----------------
__global__ __launch_bounds__(256) void k_gemm_split(
    const unsigned short* __restrict__ Ahi, const unsigned short* __restrict__ Alo,
    const unsigned short* __restrict__ BThi, const unsigned short* __restrict__ BTlo,
    const float* __restrict__ bias,
    float* __restrict__ outF,
    unsigned short* __restrict__ outHi, unsigned short* __restrict__ outLo,
    int M, int N, int K, int mode, float cscale)
{
  const int lane = threadIdx.x & 63, w = threadIdx.x >> 6;
  const int lr = lane & 15, lk = lane >> 4;
  const int rowbase = blockIdx.y*128 + (w >> 1)*64;
  const int colbase = blockIdx.x*64  + (w & 1)*32;

  f32x4 acc[4][2];
#pragma unroll
  for (int mi=0; mi<4; ++mi)
#pragma unroll
    for (int ni=0; ni<2; ++ni) acc[mi][ni] = (f32x4){0.f,0.f,0.f,0.f};

  for (int k0 = 0; k0 < K; k0 += 32){
    short8v ah[4], al[4], bh[2], bl[2];
#pragma unroll
    for (int mi=0; mi<4; ++mi){
      size_t off = (size_t)(rowbase + mi*16 + lr)*K + k0 + lk*8;
      ah[mi] = *(const short8v*)(Ahi + off);
      al[mi] = *(const short8v*)(Alo + off);
    }
#pragma unroll
    for (int ni=0; ni<2; ++ni){
      size_t off = (size_t)(colbase + ni*16 + lr)*K + k0 + lk*8;
      bh[ni] = *(const short8v*)(BThi + off);
      bl[ni] = *(const short8v*)(BTlo + off);
    }
#pragma unroll
    for (int mi=0; mi<4; ++mi)
#pragma unroll
      for (int ni=0; ni<2; ++ni){
        acc[mi][ni] = mfma16(ah[mi], bl[ni], acc[mi][ni]);
        acc[mi][ni] = mfma16(al[mi], bh[ni], acc[mi][ni]);
        acc[mi][ni] = mfma16(ah[mi], bh[ni], acc[mi][ni]);
      }
  }

#pragma unroll
  for (int mi=0; mi<4; ++mi)
#pragma unroll
    for (int ni=0; ni<2; ++ni)
#pragma unroll
      for (int r=0; r<4; ++r){
        int row = rowbase + mi*16 + lk*4 + r;   // C/D frag: row=(lane>>4)*4+r
        int col = colbase + ni*16 + lr;         //           col=lane&15
        float c = (acc[mi][ni][r] + bias[col]) * cscale;
        if (mode == 2){
          outF[(size_t)row*N + col] = c;
        } else {
          int b = row >> 11, s = row & 2047, hh = col >> 6, d = col & 63;
          size_t off = (((size_t)(b*NH + hh))*S_LEN + s)*HDIM + d;
          unsigned short hb = bf16_rne(c);
          outHi[off] = hb;
          if (mode == 0) outLo[off] = bf16_rne(c - bf16_f32(hb));
        }
      }
}

// ---------------- v [bh][s][d] -> vT [bh][d][s] (unchanged) ----------------
__global__ __launch_bounds__(256) void k_transpose_v(
    const unsigned short* __restrict__ v, unsigned short* __restrict__ vT){
  __shared__ __align__(16) unsigned short tile[64][72];
  const int bh = blockIdx.y, st = blockIdx.x;
  const int r = threadIdx.x >> 2, seg = threadIdx.x & 3;
  const unsigned short* src = v + ((size_t)bh*S_LEN + st*64 + r)*HDIM + seg*16;
  *(ushort8v*)&tile[r][seg*16]     = *(const ushort8v*)(src);
  *(ushort8v*)&tile[r][seg*16 + 8] = *(const ushort8v*)(src + 8);
  __syncthreads();
  __align__(16) unsigned short tmp[16];
#pragma unroll
  for (int i=0;i<16;++i) tmp[i] = tile[seg*16 + i][r];
  unsigned short* dst = vT + ((size_t)bh*HDIM + r)*S_LEN + st*64 + seg*16;
  *(ushort8v*)(dst)     = *(const ushort8v*)&tmp[0];
  *(ushort8v*)(dst + 8) = *(const ushort8v*)&tmp[8];
}

// ---------------- fused attention (round-3: 8-wave / 2 j-half blocks) --------
// Block: 512 threads = 8 waves; wave w: row-group wr=w&3 (16 rows), j-half
// jh=w>>2 (1024 j's). Grid 1024 blocks -> 8192 waves = 32 waves/CU.
// LDS: ts/mask staged; rowsum and PV partials combined across j-halves.

__global__ __launch_bounds__(512, 8) void k_attn(
    const unsigned short* __restrict__ qhi, const unsigned short* __restrict__ qlo,
    const unsigned short* __restrict__ khi, const unsigned short* __restrict__ klo,
    const unsigned short* __restrict__ vT,
    const float* __restrict__ ts, const int* __restrict__ am,
    const float* __restrict__ dlam,
    float* __restrict__ attn,
    unsigned short* __restrict__ ohi, unsigned short* __restrict__ olo)
{
  // LDS layout (27,648 B):
  //   0     ts_l   f32[2048]              (dead after pass 2)
  //   8192  mk_l   f32[2048]              (dead after pass 2)
  //   16384 pbuf   u16[8][16][40]         (dead after last PV)
  //   26624 rsx    f32[2][4][16]
  //   obuf  f32[4][64][20] aliases offset 0 (used only after final barrier)
  __shared__ __align__(16) char smem[27648];
  float* ts_l = (float*)(smem);
  float* mk_l = (float*)(smem + 8192);
  unsigned short* pb = (unsigned short*)(smem + 16384);
  float* rsx  = (float*)(smem + 26624);
  float* obuf = (float*)(smem);

  const int tid = threadIdx.x;
  const int w = tid >> 6, lane = tid & 63;
  const int lr = lane & 15, lk = lane >> 4;
  const int wr = w & 3, jh = w >> 2;

  // bijective XCD swizzle: 1024 blocks, 8 XCDs, 128 blocks/XCD chunk.
  const int wg = blockIdx.x;
  const int sw = (wg & 7)*128 + (wg >> 3);
  const int bh = sw >> 5;          // 0..31
  const int it = sw & 31;          // i-tile (64 rows)
  const int b = bh >> 3, h = bh & 7;
  const int i0 = it*64 + wr*16;

  const float* tsb = ts + b*S_LEN;
  const int*   amb = am + b*S_LEN;
  // stage ts + mask into LDS
  for (int i = tid; i < S_LEN; i += 512){
    ts_l[i] = tsb[i];
    mk_l[i] = amb[i] ? 1.f : 0.f;
  }

  float nlam2 = -log1pf(expf(dlam[h])) * 1.44269504f;   // -softplus(lam)*log2e
  nlam2 = __uint_as_float(__builtin_amdgcn_readfirstlane(__float_as_uint(nlam2)));

  // Q A-frags (rows i0..i0+15; q pre-scaled by 0.125*log2e at GEMM time)
  size_t qoff = ((size_t)bh*S_LEN + i0 + lr)*HDIM + lk*8;
  const short8v qh0 = *(const short8v*)(qhi + qoff);
  const short8v qh1 = *(const short8v*)(qhi + qoff + 32);
  const short8v ql0 = *(const short8v*)(qlo + qoff);
  const short8v ql1 = *(const short8v*)(qlo + qoff + 32);

  float tir[4];
#pragma unroll
  for (int r=0;r<4;++r) tir[r] = tsb[i0 + lk*4 + r];

  const unsigned short* kbhi = khi + (size_t)bh*S_LEN*HDIM;
  const unsigned short* kblo = klo + (size_t)bh*S_LEN*HDIM;
  const unsigned short* vtb  = vT  + (size_t)bh*HDIM*S_LEN;
  unsigned short* pbw = pb + w*640;           // this wave's pbuf [16][40]

  __syncthreads();   // ts_l/mk_l ready

  // ---- pass 1: partial row sums over this wave's j-half ----
  float rs0=0.f, rs1=0.f, rs2=0.f, rs3=0.f;
  {
    int koff = (jh*64)*1024 + lr*64 + lk*8;
    for (int jt = 0; jt < 64; ++jt){
      short8v kh0 = *(const short8v*)(kbhi + koff);
      short8v kh1 = *(const short8v*)(kbhi + koff + 32);
      short8v kl0 = *(const short8v*)(kblo + koff);
      short8v kl1 = *(const short8v*)(kblo + koff + 32);
      f32x4 sa = (f32x4){0.f,0.f,0.f,0.f};
      sa = mfma16(qh0, kl0, sa);
      sa = mfma16(ql0, kh0, sa);
      sa = mfma16(qh0, kh0, sa);
      sa = mfma16(qh1, kl1, sa);
      sa = mfma16(ql1, kh1, sa);
      sa = mfma16(qh1, kh1, sa);
      int jl = (jh*64 + jt)*16 + lr;
      float tj = ts_l[jl], mk = mk_l[jl];
#pragma unroll
      for (int r=0;r<4;++r){
        float dec = __builtin_amdgcn_exp2f(nlam2 * fabsf(tir[r]-tj));
        float e = __builtin_amdgcn_exp2f(sa[r]*dec) * mk;
        if (r==0) rs0 += e; else if (r==1) rs1 += e;
        else if (r==2) rs2 += e; else rs3 += e;
      }
      koff += 1024;
    }
  }
  // butterfly over the 16 lr lanes
#pragma unroll
  for (int m=1; m<16; m<<=1){
    rs0 += __shfl_xor(rs0, m, 64);
    rs1 += __shfl_xor(rs1, m, 64);
    rs2 += __shfl_xor(rs2, m, 64);
    rs3 += __shfl_xor(rs3, m, 64);
  }
  // exchange partial sums across j-halves
  if (lr == 0){
    rsx[(jh*4 + wr)*16 + lk*4 + 0] = rs0;
    rsx[(jh*4 + wr)*16 + lk*4 + 1] = rs1;
    rsx[(jh*4 + wr)*16 + lk*4 + 2] = rs2;
    rsx[(jh*4 + wr)*16 + lk*4 + 3] = rs3;
  }
  __syncthreads();
  float rinv[4];
#pragma unroll
  for (int r=0;r<4;++r){
    float tot = rsx[(wr)*16 + lk*4 + r] + rsx[(4 + wr)*16 + lk*4 + r];
    rinv[r] = tot > 0.f ? 1.f/tot : 0.f;
  }

  // uniform per-r attn row pointers (row i0+r, this j-half); lane adds lk*4 rows
  float* ar0 = attn + ((size_t)(bh*S_LEN + i0 + 0))*S_LEN + jh*1024;
  float* ar1 = ar0 + S_LEN;
  float* ar2 = ar1 + S_LEN;
  float* ar3 = ar2 + S_LEN;

  // ---- pass 2: recompute, write attn, accumulate partial PV ----
  f32x4 oacc0 = (f32x4){0.f,0.f,0.f,0.f};
  f32x4 oacc1 = (f32x4){0.f,0.f,0.f,0.f};
  f32x4 oacc2 = (f32x4){0.f,0.f,0.f,0.f};
  f32x4 oacc3 = (f32x4){0.f,0.f,0.f,0.f};

  {
    int koff  = (jh*64)*1024 + lr*64 + lk*8;
    int pvoff = lk*8192 + lr;                       // lk*4 rows + col lr
    int voff  = lr*S_LEN + jh*1024 + lk*8;
    for (int jt = 0; jt < 64; jt += 2){
#pragma unroll
      for (int half=0; half<2; ++half){
        short8v kh0 = *(const short8v*)(kbhi + koff);
        short8v kh1 = *(const short8v*)(kbhi + koff + 32);
        short8v kl0 = *(const short8v*)(kblo + koff);
        short8v kl1 = *(const short8v*)(kblo + koff + 32);
        f32x4 sa = (f32x4){0.f,0.f,0.f,0.f};
        sa = mfma16(qh0, kl0, sa);
        sa = mfma16(ql0, kh0, sa);
        sa = mfma16(qh0, kh0, sa);
        sa = mfma16(qh1, kl1, sa);
        sa = mfma16(ql1, kh1, sa);
        sa = mfma16(qh1, kh1, sa);
        int jl = (jh*64 + jt + half)*16 + lr;
        float tj = ts_l[jl], mk = mk_l[jl];
        int po = pvoff + (jt + half)*16;
#pragma unroll
        for (int r=0;r<4;++r){
          float dec = __builtin_amdgcn_exp2f(nlam2 * fabsf(tir[r]-tj));
          float e = __builtin_amdgcn_exp2f(sa[r]*dec) * mk;
          float p = e * rinv[r];
          if      (r==0) ar0[po] = p;
          else if (r==1) ar1[po] = p;
          else if (r==2) ar2[po] = p;
          else           ar3[po] = p;
          pbw[(lk*4+r)*40 + half*16 + lr] = bf16_rne(p);
        }
        koff += 1024;
      }
      // PV over this 32-j chunk (2-at-a-time vf to cap live registers)
      short8v pa = *(const short8v*)(pbw + lr*40 + lk*8);
      {
        short8v vf0 = *(const short8v*)(vtb + voff);
        short8v vf1 = *(const short8v*)(vtb + voff + 16*S_LEN);
        oacc0 = mfma16(pa, vf0, oacc0);
        oacc1 = mfma16(pa, vf1, oacc1);
      }
      {
        short8v vf2 = *(const short8v*)(vtb + voff + 32*S_LEN);
        short8v vf3 = *(const short8v*)(vtb + voff + 48*S_LEN);
        oacc2 = mfma16(pa, vf2, oacc2);
        oacc3 = mfma16(pa, vf3, oacc3);
      }
      voff += 32;
    }
  }

  // ---- combine PV partials across j-halves, write opre ----
  __syncthreads();                 // all waves done with pbuf/ts_l/mk_l
  if (jh == 1){
    int ob = (wr*64 + lane)*20;
    *(f32x4*)&obuf[ob +  0] = oacc0;
    *(f32x4*)&obuf[ob +  4] = oacc1;
    *(f32x4*)&obuf[ob +  8] = oacc2;
    *(f32x4*)&obuf[ob + 12] = oacc3;
  }
  __syncthreads();
  if (jh == 0){
    int ob = (wr*64 + lane)*20;
    oacc0 += *(const f32x4*)&obuf[ob +  0];
    oacc1 += *(const f32x4*)&obuf[ob +  4];
    oacc2 += *(const f32x4*)&obuf[ob +  8];
    oacc3 += *(const f32x4*)&obuf[ob + 12];
    float oa[4][4] = {
      {oacc0[0],oacc0[1],oacc0[2],oacc0[3]},
      {oacc1[0],oacc1[1],oacc1[2],oacc1[3]},
      {oacc2[0],oacc2[1],oacc2[2],oacc2[3]},
      {oacc3[0],oacc3[1],oacc3[2],oacc3[3]}};
#pragma unroll
    for (int nt=0;nt<4;++nt)
#pragma unroll
      for (int r=0;r<4;++r){
        int row = b*S_LEN + i0 + lk*4 + r;
        int col = h*HDIM + nt*16 + lr;
        float vv = oa[nt][r];
        unsigned short hb = bf16_rne(vv);
        ohi[(size_t)row*DM + col] = hb;
        olo[(size_t)row*DM + col] = bf16_rne(vv - bf16_f32(hb));
      }
  }
}

// ---------------------------------------------------------------------------
extern "C" void kernel_launch(void* const* d_in, const int* in_sizes, int n_in,
                              void* d_out, int out_size, void* d_ws, size_t ws_size,
                              hipStream_t stream){
  const float* x  = (const float*)d_in[0];
  const float* ts = (const float*)d_in[1];
  const int*   am = (const int*)d_in[2];
  const float* Wq = (const float*)d_in[3];
  const float* bq = (const float*)d_in[4];
  const float* Wk = (const float*)d_in[5];
  const float* bk = (const float*)d_in[6];
  const float* Wv = (const float*)d_in[7];
  const float* bv = (const float*)d_in[8];
  const float* Wo = (const float*)d_in[9];
  const float* bo = (const float*)d_in[10];
  const float* dl = (const float*)d_in[11];

  char* ws = (char*)d_ws;
  unsigned short* xhi = (unsigned short*)(ws);               // later reused as opre_hi
  unsigned short* xlo = (unsigned short*)(ws + 8388608ull);  // later reused as opre_lo
  unsigned short* wqt_hi = (unsigned short*)(ws + 16777216ull + 0ull*524288ull);
  unsigned short* wqt_lo = (unsigned short*)(ws + 16777216ull + 1ull*524288ull);
  unsigned short* wkt_hi = (unsigned short*)(ws + 16777216ull + 2ull*524288ull);
  unsigned short* wkt_lo = (unsigned short*)(ws + 16777216ull + 3ull*524288ull);
  unsigned short* wvt_hi = (unsigned short*)(ws + 16777216ull + 4ull*524288ull);
  unsigned short* wvt_lo = (unsigned short*)(ws + 16777216ull + 5ull*524288ull);
  unsigned short* wot_hi = (unsigned short*)(ws + 16777216ull + 6ull*524288ull);
  unsigned short* wot_lo = (unsigned short*)(ws + 16777216ull + 7ull*524288ull);
  unsigned short* qhi = (unsigned short*)(ws + 20971520ull + 0ull*8388608ull);
  unsigned short* qlo = (unsigned short*)(ws + 20971520ull + 1ull*8388608ull);
  unsigned short* khi = (unsigned short*)(ws + 20971520ull + 2ull*8388608ull);
  unsigned short* klo = (unsigned short*)(ws + 20971520ull + 3ull*8388608ull);
  unsigned short* vv  = (unsigned short*)(ws + 20971520ull + 4ull*8388608ull);
  unsigned short* vt  = (unsigned short*)(ws + 20971520ull + 5ull*8388608ull);

  float* outp  = (float*)d_out;
  float* attnp = outp + (size_t)BSROWS*DM;

  k_split<<<4096, 256, 0, stream>>>(x, xhi, xlo, BSROWS*DM);
  k_wsplit<<<1024, 256, 0, stream>>>(Wq, wqt_hi, wqt_lo);
  k_wsplit<<<1024, 256, 0, stream>>>(Wk, wkt_hi, wkt_lo);
  k_wsplit<<<1024, 256, 0, stream>>>(Wv, wvt_hi, wvt_lo);
  k_wsplit<<<1024, 256, 0, stream>>>(Wo, wot_hi, wot_lo);

  dim3 pg(DM/64, BSROWS/128);
  // q pre-scaled by hd^-0.5 * log2(e) = 0.125 * 1.44269504
  k_gemm_split<<<pg, 256, 0, stream>>>(xhi, xlo, wqt_hi, wqt_lo, bq,
                                       nullptr, qhi, qlo, BSROWS, DM, DM, 0,
                                       0.18033688f);
  k_gemm_split<<<pg, 256, 0, stream>>>(xhi, xlo, wkt_hi, wkt_lo, bk,
                                       nullptr, khi, klo, BSROWS, DM, DM, 0, 1.f);
  k_gemm_split<<<pg, 256, 0, stream>>>(xhi, xlo, wvt_hi, wvt_lo, bv,
                                       nullptr, vv, nullptr, BSROWS, DM, DM, 1, 1.f);
  k_transpose_v<<<dim3(S_LEN/64, BHN), 256, 0, stream>>>(vv, vt);
  k_attn<<<1024, 512, 0, stream>>>(qhi, qlo, khi, klo, vt,
                                   ts, am, dl, attnp, xhi, xlo);
  k_gemm_split<<<pg, 256, 0, stream>>>(xhi, xlo, wot_hi, wot_lo, bo,
                                       outp, nullptr, nullptr, BSROWS, DM, DM, 2, 1.f);

  (void)in_sizes; (void)n_in; (void)out_size; (void)ws_size;
}

// Round 4
// 765.382 us; speedup vs baseline: 1.2576x; 1.2576x over previous
//
#include <hip/hip_runtime.h>

// ---------------------------------------------------------------------------
// AdaptiveTemporalAttention — MI355X gfx950
// B=4, S=2048, D=512, H=8, hd=64.
// Outputs: out (B,S,D) f32 then attn (B,H,S,S) f32, concatenated in d_out.
//
// Round 4: split attention into 3 kernels, each with 2048-block grids and
// modest VGPR (round 3 showed forced-occupancy spilling is fatal; rounds 1-3
// showed the monolithic kernel is concurrency-starved at ~9-16 waves/CU).
//   k_rowsum : single-bf16 QK (2 MFMA/tile) rowsums, j-split. Error in the
//              softmax denominator averages out (~0.02% rel) — safe.
//   k_pass2  : full split-precision QK, attn write (nontemporal), PV with
//              partial-O per j-half written split-bf16 to retired buffers.
//   k_combine: partial-O add + re-split into xhi/xlo for the Wo GEMM.
// Mask folded into additive bias: e = exp2(fma(sa, dec, bias)).
// ---------------------------------------------------------------------------

#define S_LEN  2048
#define DM     512
#define NH     8
#define HDIM   64
#define BATCH  4
#define BHN    32     // BATCH*NH
#define BSROWS 8192   // BATCH*S_LEN

typedef __attribute__((ext_vector_type(8))) short short8v;
typedef __attribute__((ext_vector_type(8))) unsigned short ushort8v;
typedef __attribute__((ext_vector_type(4))) float f32x4;

static __device__ __forceinline__ unsigned short bf16_rne(float f){
  unsigned int u = __float_as_uint(f);
  u = (u + 0x7FFFu + ((u >> 16) & 1u)) >> 16;
  return (unsigned short)u;
}
static __device__ __forceinline__ float bf16_f32(unsigned short h){
  return __uint_as_float(((unsigned int)h) << 16);
}
static __device__ __forceinline__ f32x4 mfma16(short8v a, short8v b, f32x4 c){
  return __builtin_amdgcn_mfma_f32_16x16x32_bf16(a, b, c, 0, 0, 0);
}

// ---------------- prep: elementwise split f32 -> (hi,lo) bf16 ----------------
__global__ void k_split(const float* __restrict__ src,
                        unsigned short* __restrict__ hi,
                        unsigned short* __restrict__ lo, int n){
  for (int i = blockIdx.x*blockDim.x + threadIdx.x; i < n;
       i += gridDim.x*blockDim.x){
    float f = src[i];
    unsigned short h = bf16_rne(f);
    hi[i] = h;
    lo[i] = bf16_rne(f - bf16_f32(h));
  }
}

// ---------------- prep: transpose 512x512 W -> WT, split ----------------
__global__ void k_wsplit(const float* __restrict__ W,
                         unsigned short* __restrict__ Thi,
                         unsigned short* __restrict__ Tlo){
  int idx = blockIdx.x*blockDim.x + threadIdx.x; // (n,k) with k fastest
  int n = idx >> 9, k = idx & 511;
  float f = W[k*DM + n];
  unsigned short h = bf16_rne(f);
  Thi[idx] = h;
  Tlo[idx] = bf16_rne(f - bf16_f32(h));
}

// ---------------- split-precision GEMM: C = (A@B + bias)*cscale ----------------
__global__ __launch_bounds__(256) void k_gemm_split(
    const unsigned short* __restrict__ Ahi, const unsigned short* __restrict__ Alo,
    const unsigned short* __restrict__ BThi, const unsigned short* __restrict__ BTlo,
    const float* __restrict__ bias,
    float* __restrict__ outF,
    unsigned short* __restrict__ outHi, unsigned short* __restrict__ outLo,
    int M, int N, int K, int mode, float cscale)
{
  const int lane = threadIdx.x & 63, w = threadIdx.x >> 6;
  const int lr = lane & 15, lk = lane >> 4;
  const int rowbase = blockIdx.y*128 + (w >> 1)*64;
  const int colbase = blockIdx.x*64  + (w & 1)*32;

  f32x4 acc[4][2];
#pragma unroll
  for (int mi=0; mi<4; ++mi)
#pragma unroll
    for (int ni=0; ni<2; ++ni) acc[mi][ni] = (f32x4){0.f,0.f,0.f,0.f};

  for (int k0 = 0; k0 < K; k0 += 32){
    short8v ah[4], al[4], bh[2], bl[2];
#pragma unroll
    for (int mi=0; mi<4; ++mi){
      size_t off = (size_t)(rowbase + mi*16 + lr)*K + k0 + lk*8;
      ah[mi] = *(const short8v*)(Ahi + off);
      al[mi] = *(const short8v*)(Alo + off);
    }
#pragma unroll
    for (int ni=0; ni<2; ++ni){
      size_t off = (size_t)(colbase + ni*16 + lr)*K + k0 + lk*8;
      bh[ni] = *(const short8v*)(BThi + off);
      bl[ni] = *(const short8v*)(BTlo + off);
    }
#pragma unroll
    for (int mi=0; mi<4; ++mi)
#pragma unroll
      for (int ni=0; ni<2; ++ni){
        acc[mi][ni] = mfma16(ah[mi], bl[ni], acc[mi][ni]);
        acc[mi][ni] = mfma16(al[mi], bh[ni], acc[mi][ni]);
        acc[mi][ni] = mfma16(ah[mi], bh[ni], acc[mi][ni]);
      }
  }

#pragma unroll
  for (int mi=0; mi<4; ++mi)
#pragma unroll
    for (int ni=0; ni<2; ++ni)
#pragma unroll
      for (int r=0; r<4; ++r){
        int row = rowbase + mi*16 + lk*4 + r;   // C/D frag: row=(lane>>4)*4+r
        int col = colbase + ni*16 + lr;         //           col=lane&15
        float c = (acc[mi][ni][r] + bias[col]) * cscale;
        if (mode == 2){
          outF[(size_t)row*N + col] = c;
        } else {
          int b = row >> 11, s = row & 2047, hh = col >> 6, d = col & 63;
          size_t off = (((size_t)(b*NH + hh))*S_LEN + s)*HDIM + d;
          unsigned short hb = bf16_rne(c);
          outHi[off] = hb;
          if (mode == 0) outLo[off] = bf16_rne(c - bf16_f32(hb));
        }
      }
}

// ---------------- v [bh][s][d] -> vT [bh][d][s] ----------------
__global__ __launch_bounds__(256) void k_transpose_v(
    const unsigned short* __restrict__ v, unsigned short* __restrict__ vT){
  __shared__ __align__(16) unsigned short tile[64][72];
  const int bh = blockIdx.y, st = blockIdx.x;
  const int r = threadIdx.x >> 2, seg = threadIdx.x & 3;
  const unsigned short* src = v + ((size_t)bh*S_LEN + st*64 + r)*HDIM + seg*16;
  *(ushort8v*)&tile[r][seg*16]     = *(const ushort8v*)(src);
  *(ushort8v*)&tile[r][seg*16 + 8] = *(const ushort8v*)(src + 8);
  __syncthreads();
  __align__(16) unsigned short tmp[16];
#pragma unroll
  for (int i=0;i<16;++i) tmp[i] = tile[seg*16 + i][r];
  unsigned short* dst = vT + ((size_t)bh*HDIM + r)*S_LEN + st*64 + seg*16;
  *(ushort8v*)(dst)     = *(const ushort8v*)&tmp[0];
  *(ushort8v*)(dst + 8) = *(const ushort8v*)&tmp[8];
}

// ---------------- rowsum kernel (single-bf16 QK, 2 MFMA/tile) ----------------
// grid 2048 = (bh x i-tile x j-half), 256 thr = 4 waves x 16 rows.
// rs_part layout: f32[jh][bh][2048].
__global__ __launch_bounds__(256) void k_rowsum(
    const unsigned short* __restrict__ qhi,
    const unsigned short* __restrict__ khi,
    const float* __restrict__ ts, const int* __restrict__ am,
    const float* __restrict__ dlam,
    float* __restrict__ rs_part)
{
  __shared__ float2 tsmk[1024];
  const int w = threadIdx.x >> 6, lane = threadIdx.x & 63;
  const int lr = lane & 15, lk = lane >> 4;
  // XCD swizzle: 2048 blocks, 8 XCDs, 256/chunk; same bh stays on one XCD.
  const int wg = blockIdx.x;
  const int sw = (wg & 7)*256 + (wg >> 3);
  const int bh = sw >> 6, rem = sw & 63, it = rem >> 1, jh = rem & 1;
  const int b = bh >> 3, h = bh & 7;
  const int i0 = it*64 + w*16;
  const int j0 = jh*1024;

  const float* tsb = ts + b*S_LEN;
  const int*   amb = am + b*S_LEN;
  for (int i = threadIdx.x; i < 1024; i += 256)
    tsmk[i] = make_float2(tsb[j0+i], amb[j0+i] ? 0.f : -1e30f);

  float nlam2 = -log1pf(expf(dlam[h])) * 1.44269504f;
  nlam2 = __uint_as_float(__builtin_amdgcn_readfirstlane(__float_as_uint(nlam2)));

  size_t qoff = ((size_t)bh*S_LEN + i0 + lr)*HDIM + lk*8;
  const short8v qh0 = *(const short8v*)(qhi + qoff);
  const short8v qh1 = *(const short8v*)(qhi + qoff + 32);
  float tir[4];
#pragma unroll
  for (int r=0;r<4;++r) tir[r] = tsb[i0 + lk*4 + r];

  const unsigned short* kb = khi + ((size_t)bh*S_LEN + j0)*HDIM;
  __syncthreads();

  float rs0=0.f, rs1=0.f, rs2=0.f, rs3=0.f;
  int koff = lr*HDIM + lk*8;
  for (int jt = 0; jt < 64; jt += 2){
    short8v a0 = *(const short8v*)(kb + koff);
    short8v a1 = *(const short8v*)(kb + koff + 32);
    short8v c0 = *(const short8v*)(kb + koff + 1024);
    short8v c1 = *(const short8v*)(kb + koff + 1024 + 32);
    f32x4 sA = (f32x4){0.f,0.f,0.f,0.f};
    sA = mfma16(qh0, a0, sA);
    sA = mfma16(qh1, a1, sA);
    f32x4 sB = (f32x4){0.f,0.f,0.f,0.f};
    sB = mfma16(qh0, c0, sB);
    sB = mfma16(qh1, c1, sB);
    float2 tmA = tsmk[jt*16 + lr];
    float2 tmB = tsmk[jt*16 + 16 + lr];
#pragma unroll
    for (int r=0;r<4;++r){
      float decA = __builtin_amdgcn_exp2f(nlam2 * fabsf(tir[r]-tmA.x));
      float eA = __builtin_amdgcn_exp2f(__builtin_fmaf(sA[r], decA, tmA.y));
      float decB = __builtin_amdgcn_exp2f(nlam2 * fabsf(tir[r]-tmB.x));
      float eB = __builtin_amdgcn_exp2f(__builtin_fmaf(sB[r], decB, tmB.y));
      float e = eA + eB;
      if (r==0) rs0 += e; else if (r==1) rs1 += e;
      else if (r==2) rs2 += e; else rs3 += e;
    }
    koff += 2048;
  }
#pragma unroll
  for (int m=1; m<16; m<<=1){
    rs0 += __shfl_xor(rs0, m, 64);
    rs1 += __shfl_xor(rs1, m, 64);
    rs2 += __shfl_xor(rs2, m, 64);
    rs3 += __shfl_xor(rs3, m, 64);
  }
  if (lr == 0){
    float* dst = rs_part + (size_t)(jh*BHN + bh)*S_LEN + i0 + lk*4;
    dst[0] = rs0; dst[1] = rs1; dst[2] = rs2; dst[3] = rs3;
  }
}

// ---------------- pass-2 kernel: attn write + partial PV ----------------
// grid 2048 = (bh x i-tile x j-half), 256 thr = 4 waves x 16 rows.
// Partial O (split bf16): jh=0 -> (p0hi,p0lo), jh=1 -> (p1hi,p1lo),
// both at [row=b*S+s][col=h*64+d].
__global__ __launch_bounds__(256, 5) void k_pass2(
    const unsigned short* __restrict__ qhi, const unsigned short* __restrict__ qlo,
    const unsigned short* __restrict__ khi, const unsigned short* __restrict__ klo,
    const unsigned short* __restrict__ vT,
    const float* __restrict__ ts, const int* __restrict__ am,
    const float* __restrict__ dlam,
    const float* __restrict__ rs_part,
    float* __restrict__ attn,
    unsigned short* __restrict__ p0hi, unsigned short* __restrict__ p0lo,
    unsigned short* __restrict__ p1hi, unsigned short* __restrict__ p1lo)
{
  __shared__ float2 tsmk[1024];
  __shared__ __align__(16) unsigned short pb[4][16][40];
  const int w = threadIdx.x >> 6, lane = threadIdx.x & 63;
  const int lr = lane & 15, lk = lane >> 4;
  const int wg = blockIdx.x;
  const int sw = (wg & 7)*256 + (wg >> 3);
  const int bh = sw >> 6, rem = sw & 63, it = rem >> 1, jh = rem & 1;
  const int b = bh >> 3, h = bh & 7;
  const int i0 = it*64 + w*16;
  const int j0 = jh*1024;

  const float* tsb = ts + b*S_LEN;
  const int*   amb = am + b*S_LEN;
  for (int i = threadIdx.x; i < 1024; i += 256)
    tsmk[i] = make_float2(tsb[j0+i], amb[j0+i] ? 0.f : -1e30f);

  float nlam2 = -log1pf(expf(dlam[h])) * 1.44269504f;
  nlam2 = __uint_as_float(__builtin_amdgcn_readfirstlane(__float_as_uint(nlam2)));

  size_t qoff = ((size_t)bh*S_LEN + i0 + lr)*HDIM + lk*8;
  const short8v qh0 = *(const short8v*)(qhi + qoff);
  const short8v qh1 = *(const short8v*)(qhi + qoff + 32);
  const short8v ql0 = *(const short8v*)(qlo + qoff);
  const short8v ql1 = *(const short8v*)(qlo + qoff + 32);

  float tir[4], rinv[4];
#pragma unroll
  for (int r=0;r<4;++r){
    int row = i0 + lk*4 + r;
    tir[r] = tsb[row];
    float tot = rs_part[(size_t)bh*S_LEN + row]
              + rs_part[(size_t)(BHN + bh)*S_LEN + row];
    rinv[r] = tot > 0.f ? 1.f/tot : 0.f;
  }

  const unsigned short* kbh = khi + ((size_t)bh*S_LEN + j0)*HDIM;
  const unsigned short* kbl = klo + ((size_t)bh*S_LEN + j0)*HDIM;
  const unsigned short* vtb = vT + (size_t)bh*HDIM*S_LEN;
  unsigned short* pbw = &pb[w][0][0];

  // 32-bit element offsets into attn (max ~134M < 2^31)
  unsigned int aoff[4];
#pragma unroll
  for (int r=0;r<4;++r)
    aoff[r] = (unsigned int)(bh*S_LEN + i0 + lk*4 + r)*S_LEN + j0;

  __syncthreads();

  f32x4 oacc0 = (f32x4){0.f,0.f,0.f,0.f};
  f32x4 oacc1 = (f32x4){0.f,0.f,0.f,0.f};
  f32x4 oacc2 = (f32x4){0.f,0.f,0.f,0.f};
  f32x4 oacc3 = (f32x4){0.f,0.f,0.f,0.f};

  int koff = lr*HDIM + lk*8;
  int voff = lr*S_LEN + j0 + lk*8;
  for (int jt = 0; jt < 64; jt += 2){
#pragma unroll
    for (int half=0; half<2; ++half){
      short8v kh0 = *(const short8v*)(kbh + koff);
      short8v kh1 = *(const short8v*)(kbh + koff + 32);
      short8v kl0 = *(const short8v*)(kbl + koff);
      short8v kl1 = *(const short8v*)(kbl + koff + 32);
      // split accumulators: 4-chain (corrections) + 2-chain (leading)
      f32x4 s1 = (f32x4){0.f,0.f,0.f,0.f};
      s1 = mfma16(qh0, kl0, s1);
      s1 = mfma16(ql0, kh0, s1);
      s1 = mfma16(qh1, kl1, s1);
      s1 = mfma16(ql1, kh1, s1);
      f32x4 s2 = (f32x4){0.f,0.f,0.f,0.f};
      s2 = mfma16(qh0, kh0, s2);
      s2 = mfma16(qh1, kh1, s2);
      float2 tm = tsmk[(jt+half)*16 + lr];
      unsigned int po = (jt+half)*16 + lr;
#pragma unroll
      for (int r=0;r<4;++r){
        float sa = s1[r] + s2[r];
        float dec = __builtin_amdgcn_exp2f(nlam2 * fabsf(tir[r]-tm.x));
        float e = __builtin_amdgcn_exp2f(__builtin_fmaf(sa, dec, tm.y));
        float p = e * rinv[r];
        __builtin_nontemporal_store(p, attn + aoff[r] + po);
        pbw[(lk*4+r)*40 + half*16 + lr] = bf16_rne(p);
      }
      koff += 1024;
    }
    short8v pa = *(const short8v*)(pbw + lr*40 + lk*8);
    {
      short8v vf0 = *(const short8v*)(vtb + voff);
      short8v vf1 = *(const short8v*)(vtb + voff + 16*S_LEN);
      oacc0 = mfma16(pa, vf0, oacc0);
      oacc1 = mfma16(pa, vf1, oacc1);
    }
    {
      short8v vf2 = *(const short8v*)(vtb + voff + 32*S_LEN);
      short8v vf3 = *(const short8v*)(vtb + voff + 48*S_LEN);
      oacc2 = mfma16(pa, vf2, oacc2);
      oacc3 = mfma16(pa, vf3, oacc3);
    }
    voff += 32;
  }

  unsigned short* phi = jh ? p1hi : p0hi;
  unsigned short* plo = jh ? p1lo : p0lo;
  float oa[4][4] = {
    {oacc0[0],oacc0[1],oacc0[2],oacc0[3]},
    {oacc1[0],oacc1[1],oacc1[2],oacc1[3]},
    {oacc2[0],oacc2[1],oacc2[2],oacc2[3]},
    {oacc3[0],oacc3[1],oacc3[2],oacc3[3]}};
#pragma unroll
  for (int nt=0;nt<4;++nt)
#pragma unroll
    for (int r=0;r<4;++r){
      int row = b*S_LEN + i0 + lk*4 + r;
      int col = h*HDIM + nt*16 + lr;
      float vv = oa[nt][r];
      unsigned short hb = bf16_rne(vv);
      phi[(size_t)row*DM + col] = hb;
      plo[(size_t)row*DM + col] = bf16_rne(vv - bf16_f32(hb));
    }
}

// ---------------- combine partial O halves -> split bf16 into (oh,ol) --------
__global__ __launch_bounds__(256) void k_combine(
    const unsigned short* __restrict__ h1, const unsigned short* __restrict__ l1,
    unsigned short* __restrict__ oh, unsigned short* __restrict__ ol, int n8)
{
  int i = blockIdx.x*blockDim.x + threadIdx.x;
  if (i >= n8) return;
  size_t base = (size_t)i*8;
  ushort8v a = *(const ushort8v*)(oh + base);   // jh=0 hi (in place)
  ushort8v bq = *(const ushort8v*)(ol + base);  // jh=0 lo
  ushort8v c = *(const ushort8v*)(h1 + base);
  ushort8v d = *(const ushort8v*)(l1 + base);
  ushort8v rh, rl;
#pragma unroll
  for (int j=0;j<8;++j){
    float f = bf16_f32(a[j]) + bf16_f32(bq[j]) + bf16_f32(c[j]) + bf16_f32(d[j]);
    unsigned short hb = bf16_rne(f);
    rh[j] = hb;
    rl[j] = bf16_rne(f - bf16_f32(hb));
  }
  *(ushort8v*)(oh + base) = rh;
  *(ushort8v*)(ol + base) = rl;
}

// ---------------------------------------------------------------------------
extern "C" void kernel_launch(void* const* d_in, const int* in_sizes, int n_in,
                              void* d_out, int out_size, void* d_ws, size_t ws_size,
                              hipStream_t stream){
  const float* x  = (const float*)d_in[0];
  const float* ts = (const float*)d_in[1];
  const int*   am = (const int*)d_in[2];
  const float* Wq = (const float*)d_in[3];
  const float* bq = (const float*)d_in[4];
  const float* Wk = (const float*)d_in[5];
  const float* bk = (const float*)d_in[6];
  const float* Wv = (const float*)d_in[7];
  const float* bv = (const float*)d_in[8];
  const float* Wo = (const float*)d_in[9];
  const float* bo = (const float*)d_in[10];
  const float* dl = (const float*)d_in[11];

  char* ws = (char*)d_ws;
  unsigned short* xhi = (unsigned short*)(ws);               // x-split; later partial/final opre hi
  unsigned short* xlo = (unsigned short*)(ws + 8388608ull);  // x-split; later partial/final opre lo
  unsigned short* wqt_hi = (unsigned short*)(ws + 16777216ull + 0ull*524288ull);
  unsigned short* wqt_lo = (unsigned short*)(ws + 16777216ull + 1ull*524288ull);
  unsigned short* wkt_hi = (unsigned short*)(ws + 16777216ull + 2ull*524288ull);
  unsigned short* wkt_lo = (unsigned short*)(ws + 16777216ull + 3ull*524288ull);
  unsigned short* wvt_hi = (unsigned short*)(ws + 16777216ull + 4ull*524288ull);
  unsigned short* wvt_lo = (unsigned short*)(ws + 16777216ull + 5ull*524288ull);
  unsigned short* wot_hi = (unsigned short*)(ws + 16777216ull + 6ull*524288ull);
  unsigned short* wot_lo = (unsigned short*)(ws + 16777216ull + 7ull*524288ull);
  unsigned short* qhi = (unsigned short*)(ws + 20971520ull + 0ull*8388608ull);
  unsigned short* qlo = (unsigned short*)(ws + 20971520ull + 1ull*8388608ull);
  unsigned short* khi = (unsigned short*)(ws + 20971520ull + 2ull*8388608ull);
  unsigned short* klo = (unsigned short*)(ws + 20971520ull + 3ull*8388608ull);
  unsigned short* vv  = (unsigned short*)(ws + 20971520ull + 4ull*8388608ull);
  unsigned short* vt  = (unsigned short*)(ws + 20971520ull + 5ull*8388608ull);
  // rs_part reuses the retired Wq slot (free after the q GEMM): 512 KB
  float* rs_part = (float*)(ws + 16777216ull);

  float* outp  = (float*)d_out;
  float* attnp = outp + (size_t)BSROWS*DM;
  // jh=1 partial O stashed in the out0 region (scratch until final GEMM)
  unsigned short* p1hi = (unsigned short*)d_out;
  unsigned short* p1lo = p1hi + 4194304ull;

  k_split<<<4096, 256, 0, stream>>>(x, xhi, xlo, BSROWS*DM);
  k_wsplit<<<1024, 256, 0, stream>>>(Wq, wqt_hi, wqt_lo);
  k_wsplit<<<1024, 256, 0, stream>>>(Wk, wkt_hi, wkt_lo);
  k_wsplit<<<1024, 256, 0, stream>>>(Wv, wvt_hi, wvt_lo);
  k_wsplit<<<1024, 256, 0, stream>>>(Wo, wot_hi, wot_lo);

  dim3 pg(DM/64, BSROWS/128);
  // q pre-scaled by hd^-0.5 * log2(e)
  k_gemm_split<<<pg, 256, 0, stream>>>(xhi, xlo, wqt_hi, wqt_lo, bq,
                                       nullptr, qhi, qlo, BSROWS, DM, DM, 0,
                                       0.18033688f);
  k_gemm_split<<<pg, 256, 0, stream>>>(xhi, xlo, wkt_hi, wkt_lo, bk,
                                       nullptr, khi, klo, BSROWS, DM, DM, 0, 1.f);
  k_gemm_split<<<pg, 256, 0, stream>>>(xhi, xlo, wvt_hi, wvt_lo, bv,
                                       nullptr, vv, nullptr, BSROWS, DM, DM, 1, 1.f);
  k_transpose_v<<<dim3(S_LEN/64, BHN), 256, 0, stream>>>(vv, vt);

  // NOTE: rs_part overwrites the Wq slot — q GEMM is already done.
  k_rowsum<<<2048, 256, 0, stream>>>(qhi, khi, ts, am, dl, rs_part);
  k_pass2<<<2048, 256, 0, stream>>>(qhi, qlo, khi, klo, vt, ts, am, dl,
                                    rs_part, attnp, xhi, xlo, p1hi, p1lo);
  k_combine<<<2048, 256, 0, stream>>>(p1hi, p1lo, xhi, xlo, 524288);
  k_gemm_split<<<pg, 256, 0, stream>>>(xhi, xlo, wot_hi, wot_lo, bo,
                                       outp, nullptr, nullptr, BSROWS, DM, DM, 2, 1.f);

  (void)in_sizes; (void)n_in; (void)out_size; (void)ws_size;
}

// Round 5
// 756.696 us; speedup vs baseline: 1.2720x; 1.0115x over previous
//
#include <hip/hip_runtime.h>

// ---------------------------------------------------------------------------
// AdaptiveTemporalAttention — MI355X gfx950
// B=4, S=2048, D=512, H=8, hd=64.
// Outputs: out (B,S,D) f32 then attn (B,H,S,S) f32, concatenated in d_out.
//
// Round 5: operand-swapped QK (S^T = mfma(A=K,B=Q)) in k_rowsum/k_pass2 so
// each lane owns 4 CONSECUTIVE j's of one row i=lr. This turns the attn
// write into one plain dwordx4 store per 16-j subtile (was 4 scalar
// nontemporal stores sharing the vmcnt FIFO with K loads — suspected
// store-drain serialization), shrinks the P LDS transpose to 2 b64 writes +
// 1 b128 read, and simplifies rowsum to a scalar + 2 shuffles.
// ---------------------------------------------------------------------------

#define S_LEN  2048
#define DM     512
#define NH     8
#define HDIM   64
#define BATCH  4
#define BHN    32     // BATCH*NH
#define BSROWS 8192   // BATCH*S_LEN

typedef __attribute__((ext_vector_type(8))) short short8v;
typedef __attribute__((ext_vector_type(8))) unsigned short ushort8v;
typedef __attribute__((ext_vector_type(4))) unsigned short ushort4v;
typedef __attribute__((ext_vector_type(4))) float f32x4;
typedef __attribute__((ext_vector_type(2))) unsigned int uint2v;

static __device__ __forceinline__ unsigned short bf16_rne(float f){
  unsigned int u = __float_as_uint(f);
  u = (u + 0x7FFFu + ((u >> 16) & 1u)) >> 16;
  return (unsigned short)u;
}
static __device__ __forceinline__ float bf16_f32(unsigned short h){
  return __uint_as_float(((unsigned int)h) << 16);
}
static __device__ __forceinline__ unsigned int pack2bf(float a, float b){
  return (unsigned int)bf16_rne(a) | ((unsigned int)bf16_rne(b) << 16);
}
static __device__ __forceinline__ f32x4 mfma16(short8v a, short8v b, f32x4 c){
  return __builtin_amdgcn_mfma_f32_16x16x32_bf16(a, b, c, 0, 0, 0);
}

// ---------------- prep: elementwise split f32 -> (hi,lo) bf16 ----------------
__global__ void k_split(const float* __restrict__ src,
                        unsigned short* __restrict__ hi,
                        unsigned short* __restrict__ lo, int n){
  for (int i = blockIdx.x*blockDim.x + threadIdx.x; i < n;
       i += gridDim.x*blockDim.x){
    float f = src[i];
    unsigned short h = bf16_rne(f);
    hi[i] = h;
    lo[i] = bf16_rne(f - bf16_f32(h));
  }
}

// ---------------- prep: transpose 512x512 W -> WT, split ----------------
__global__ void k_wsplit(const float* __restrict__ W,
                         unsigned short* __restrict__ Thi,
                         unsigned short* __restrict__ Tlo){
  int idx = blockIdx.x*blockDim.x + threadIdx.x; // (n,k) with k fastest
  int n = idx >> 9, k = idx & 511;
  float f = W[k*DM + n];
  unsigned short h = bf16_rne(f);
  Thi[idx] = h;
  Tlo[idx] = bf16_rne(f - bf16_f32(h));
}

// ---------------- split-precision GEMM: C = (A@B + bias)*cscale ----------------
__global__ __launch_bounds__(256) void k_gemm_split(
    const unsigned short* __restrict__ Ahi, const unsigned short* __restrict__ Alo,
    const unsigned short* __restrict__ BThi, const unsigned short* __restrict__ BTlo,
    const float* __restrict__ bias,
    float* __restrict__ outF,
    unsigned short* __restrict__ outHi, unsigned short* __restrict__ outLo,
    int M, int N, int K, int mode, float cscale)
{
  const int lane = threadIdx.x & 63, w = threadIdx.x >> 6;
  const int lr = lane & 15, lk = lane >> 4;
  const int rowbase = blockIdx.y*128 + (w >> 1)*64;
  const int colbase = blockIdx.x*64  + (w & 1)*32;

  f32x4 acc[4][2];
#pragma unroll
  for (int mi=0; mi<4; ++mi)
#pragma unroll
    for (int ni=0; ni<2; ++ni) acc[mi][ni] = (f32x4){0.f,0.f,0.f,0.f};

  for (int k0 = 0; k0 < K; k0 += 32){
    short8v ah[4], al[4], bh[2], bl[2];
#pragma unroll
    for (int mi=0; mi<4; ++mi){
      size_t off = (size_t)(rowbase + mi*16 + lr)*K + k0 + lk*8;
      ah[mi] = *(const short8v*)(Ahi + off);
      al[mi] = *(const short8v*)(Alo + off);
    }
#pragma unroll
    for (int ni=0; ni<2; ++ni){
      size_t off = (size_t)(colbase + ni*16 + lr)*K + k0 + lk*8;
      bh[ni] = *(const short8v*)(BThi + off);
      bl[ni] = *(const short8v*)(BTlo + off);
    }
#pragma unroll
    for (int mi=0; mi<4; ++mi)
#pragma unroll
      for (int ni=0; ni<2; ++ni){
        acc[mi][ni] = mfma16(ah[mi], bl[ni], acc[mi][ni]);
        acc[mi][ni] = mfma16(al[mi], bh[ni], acc[mi][ni]);
        acc[mi][ni] = mfma16(ah[mi], bh[ni], acc[mi][ni]);
      }
  }

#pragma unroll
  for (int mi=0; mi<4; ++mi)
#pragma unroll
    for (int ni=0; ni<2; ++ni)
#pragma unroll
      for (int r=0; r<4; ++r){
        int row = rowbase + mi*16 + lk*4 + r;   // C/D frag: row=(lane>>4)*4+r
        int col = colbase + ni*16 + lr;         //           col=lane&15
        float c = (acc[mi][ni][r] + bias[col]) * cscale;
        if (mode == 2){
          outF[(size_t)row*N + col] = c;
        } else {
          int b = row >> 11, s = row & 2047, hh = col >> 6, d = col & 63;
          size_t off = (((size_t)(b*NH + hh))*S_LEN + s)*HDIM + d;
          unsigned short hb = bf16_rne(c);
          outHi[off] = hb;
          if (mode == 0) outLo[off] = bf16_rne(c - bf16_f32(hb));
        }
      }
}

// ---------------- v [bh][s][d] -> vT [bh][d][s] ----------------
__global__ __launch_bounds__(256) void k_transpose_v(
    const unsigned short* __restrict__ v, unsigned short* __restrict__ vT){
  __shared__ __align__(16) unsigned short tile[64][72];
  const int bh = blockIdx.y, st = blockIdx.x;
  const int r = threadIdx.x >> 2, seg = threadIdx.x & 3;
  const unsigned short* src = v + ((size_t)bh*S_LEN + st*64 + r)*HDIM + seg*16;
  *(ushort8v*)&tile[r][seg*16]     = *(const ushort8v*)(src);
  *(ushort8v*)&tile[r][seg*16 + 8] = *(const ushort8v*)(src + 8);
  __syncthreads();
  __align__(16) unsigned short tmp[16];
#pragma unroll
  for (int i=0;i<16;++i) tmp[i] = tile[seg*16 + i][r];
  unsigned short* dst = vT + ((size_t)bh*HDIM + r)*S_LEN + st*64 + seg*16;
  *(ushort8v*)(dst)     = *(const ushort8v*)&tmp[0];
  *(ushort8v*)(dst + 8) = *(const ushort8v*)&tmp[8];
}

// ---------------- rowsum kernel (swapped: S^T = mfma(K, Q), hi-only) ---------
// grid 2048 = (bh x i-tile x j-half), 256 thr = 4 waves x 16 rows.
// Lane (lr,lk): row i = i0+lr, j = jt*16 + lk*4 + r. rs_part: f32[jh][bh][2048].
__global__ __launch_bounds__(256) void k_rowsum(
    const unsigned short* __restrict__ qhi,
    const unsigned short* __restrict__ khi,
    const float* __restrict__ ts, const int* __restrict__ am,
    const float* __restrict__ dlam,
    float* __restrict__ rs_part)
{
  __shared__ __align__(16) float ts_l[1024];
  __shared__ __align__(16) float mb_l[1024];
  const int w = threadIdx.x >> 6, lane = threadIdx.x & 63;
  const int lr = lane & 15, lk = lane >> 4;
  const int wg = blockIdx.x;
  const int sw = (wg & 7)*256 + (wg >> 3);
  const int bh = sw >> 6, rem = sw & 63, it = rem >> 1, jh = rem & 1;
  const int b = bh >> 3, h = bh & 7;
  const int i0 = it*64 + w*16;
  const int j0 = jh*1024;

  const float* tsb = ts + b*S_LEN;
  const int*   amb = am + b*S_LEN;
  for (int i = threadIdx.x; i < 1024; i += 256){
    ts_l[i] = tsb[j0+i];
    mb_l[i] = amb[j0+i] ? 0.f : -1e30f;
  }

  float nlam2 = -log1pf(expf(dlam[h])) * 1.44269504f;
  nlam2 = __uint_as_float(__builtin_amdgcn_readfirstlane(__float_as_uint(nlam2)));

  // Q B-frag: col=lane&15 -> i=lr, k=(lane>>4)*8+e -> d
  size_t qoff = ((size_t)bh*S_LEN + i0 + lr)*HDIM + lk*8;
  const short8v qh0 = *(const short8v*)(qhi + qoff);
  const short8v qh1 = *(const short8v*)(qhi + qoff + 32);
  const float ti = tsb[i0 + lr];

  const unsigned short* kb = khi + ((size_t)bh*S_LEN + j0)*HDIM;
  __syncthreads();

  float rs = 0.f;
  int koff = lr*HDIM + lk*8;
  for (int jt = 0; jt < 64; jt += 2){
    short8v a0 = *(const short8v*)(kb + koff);
    short8v a1 = *(const short8v*)(kb + koff + 32);
    short8v c0 = *(const short8v*)(kb + koff + 1024);
    short8v c1 = *(const short8v*)(kb + koff + 1024 + 32);
    f32x4 sA = (f32x4){0.f,0.f,0.f,0.f};
    sA = mfma16(a0, qh0, sA);
    sA = mfma16(a1, qh1, sA);
    f32x4 sB = (f32x4){0.f,0.f,0.f,0.f};
    sB = mfma16(c0, qh0, sB);
    sB = mfma16(c1, qh1, sB);
    f32x4 tsA = *(const f32x4*)&ts_l[jt*16 + lk*4];
    f32x4 mbA = *(const f32x4*)&mb_l[jt*16 + lk*4];
    f32x4 tsB = *(const f32x4*)&ts_l[jt*16 + 16 + lk*4];
    f32x4 mbB = *(const f32x4*)&mb_l[jt*16 + 16 + lk*4];
#pragma unroll
    for (int r=0;r<4;++r){
      float decA = __builtin_amdgcn_exp2f(nlam2 * fabsf(ti - tsA[r]));
      rs += __builtin_amdgcn_exp2f(__builtin_fmaf(sA[r], decA, mbA[r]));
      float decB = __builtin_amdgcn_exp2f(nlam2 * fabsf(ti - tsB[r]));
      rs += __builtin_amdgcn_exp2f(__builtin_fmaf(sB[r], decB, mbB[r]));
    }
    koff += 2048;
  }
  // reduce over the 4 lk groups (lane bits 4-5)
  rs += __shfl_xor(rs, 16, 64);
  rs += __shfl_xor(rs, 32, 64);
  if (lane < 16)
    rs_part[(size_t)(jh*BHN + bh)*S_LEN + i0 + lane] = rs;
}

// ---------------- pass-2: attn write (coalesced dwordx4) + partial PV --------
// grid 2048 = (bh x i-tile x j-half), 256 thr = 4 waves x 16 rows.
// Swapped QK: lane (lr,lk) owns row i=i0+lr, j = jt*16+lk*4+r (4 consecutive).
// attn: ONE dwordx4 store per subtile. P->PV via tiny LDS transpose
// (2 x ds_write_b64 + 1 x ds_read_b128 per 32-j chunk, 20-u32 padded rows).
// PV computes O^T = mfma(A=V^T, B=P^T); pa (B-frag) = P[i=lr][j=8*lk+e].
__global__ __launch_bounds__(256, 4) void k_pass2(
    const unsigned short* __restrict__ qhi, const unsigned short* __restrict__ qlo,
    const unsigned short* __restrict__ khi, const unsigned short* __restrict__ klo,
    const unsigned short* __restrict__ vT,
    const float* __restrict__ ts, const int* __restrict__ am,
    const float* __restrict__ dlam,
    const float* __restrict__ rs_part,
    float* __restrict__ attn,
    unsigned short* __restrict__ p0hi, unsigned short* __restrict__ p0lo,
    unsigned short* __restrict__ p1hi, unsigned short* __restrict__ p1lo)
{
  __shared__ __align__(16) float ts_l[1024];
  __shared__ __align__(16) float mb_l[1024];
  __shared__ __align__(16) unsigned int pb[4][16][20];  // [wave][i-row][pad 20]
  const int w = threadIdx.x >> 6, lane = threadIdx.x & 63;
  const int lr = lane & 15, lk = lane >> 4;
  const int wg = blockIdx.x;
  const int sw = (wg & 7)*256 + (wg >> 3);
  const int bh = sw >> 6, rem = sw & 63, it = rem >> 1, jh = rem & 1;
  const int b = bh >> 3, h = bh & 7;
  const int i0 = it*64 + w*16;
  const int j0 = jh*1024;

  const float* tsb = ts + b*S_LEN;
  const int*   amb = am + b*S_LEN;
  for (int i = threadIdx.x; i < 1024; i += 256){
    ts_l[i] = tsb[j0+i];
    mb_l[i] = amb[j0+i] ? 0.f : -1e30f;
  }

  float nlam2 = -log1pf(expf(dlam[h])) * 1.44269504f;
  nlam2 = __uint_as_float(__builtin_amdgcn_readfirstlane(__float_as_uint(nlam2)));

  size_t qoff = ((size_t)bh*S_LEN + i0 + lr)*HDIM + lk*8;
  const short8v qh0 = *(const short8v*)(qhi + qoff);
  const short8v qh1 = *(const short8v*)(qhi + qoff + 32);
  const short8v ql0 = *(const short8v*)(qlo + qoff);
  const short8v ql1 = *(const short8v*)(qlo + qoff + 32);
  const float ti = tsb[i0 + lr];

  float tot = rs_part[(size_t)bh*S_LEN + i0 + lr]
            + rs_part[(size_t)(BHN + bh)*S_LEN + i0 + lr];
  const float rinv = tot > 0.f ? 1.f/tot : 0.f;

  const unsigned short* kbh = khi + ((size_t)bh*S_LEN + j0)*HDIM;
  const unsigned short* kbl = klo + ((size_t)bh*S_LEN + j0)*HDIM;
  const unsigned short* vtb = vT + (size_t)bh*HDIM*S_LEN;
  unsigned int* pbw = &pb[w][0][0];

  // this lane's attn row base (element offset, fits in u32: < 2^27)
  const unsigned int abase = (unsigned int)(bh*S_LEN + i0 + lr)*S_LEN + j0;

  __syncthreads();

  f32x4 oaccT0 = (f32x4){0.f,0.f,0.f,0.f};
  f32x4 oaccT1 = (f32x4){0.f,0.f,0.f,0.f};
  f32x4 oaccT2 = (f32x4){0.f,0.f,0.f,0.f};
  f32x4 oaccT3 = (f32x4){0.f,0.f,0.f,0.f};

  int koff = lr*HDIM + lk*8;
  int voff = lr*S_LEN + j0 + lk*8;
  for (int jt = 0; jt < 64; jt += 2){
#pragma unroll
    for (int half=0; half<2; ++half){
      short8v kh0 = *(const short8v*)(kbh + koff);
      short8v kh1 = *(const short8v*)(kbh + koff + 32);
      short8v kl0 = *(const short8v*)(kbl + koff);
      short8v kl1 = *(const short8v*)(kbl + koff + 32);
      // swapped: S^T tile; split accumulators (4-chain corrections + 2-chain hi)
      f32x4 s1 = (f32x4){0.f,0.f,0.f,0.f};
      s1 = mfma16(kh0, ql0, s1);
      s1 = mfma16(kl0, qh0, s1);
      s1 = mfma16(kh1, ql1, s1);
      s1 = mfma16(kl1, qh1, s1);
      f32x4 s2 = (f32x4){0.f,0.f,0.f,0.f};
      s2 = mfma16(kh0, qh0, s2);
      s2 = mfma16(kh1, qh1, s2);
      const int jb = (jt+half)*16 + lk*4;
      f32x4 ts4 = *(const f32x4*)&ts_l[jb];
      f32x4 mb4 = *(const f32x4*)&mb_l[jb];
      f32x4 pv;
#pragma unroll
      for (int r=0;r<4;++r){
        float sa = s1[r] + s2[r];
        float dec = __builtin_amdgcn_exp2f(nlam2 * fabsf(ti - ts4[r]));
        float e = __builtin_amdgcn_exp2f(__builtin_fmaf(sa, dec, mb4[r]));
        pv[r] = e * rinv;
      }
      // ONE coalesced 16B store: row i0+lr, cols jb..jb+3
      *(f32x4*)(attn + abase + jb) = pv;
      // stage packed bf16 pairs for PV: row lr, u32 cols {half*8 + 2lk, +1}
      uint2v pk; pk.x = pack2bf(pv[0], pv[1]); pk.y = pack2bf(pv[2], pv[3]);
      *(uint2v*)&pbw[lr*20 + half*8 + 2*lk] = pk;
      koff += 1024;
    }
    // PV for this 32-j chunk: pa = P[i=lr][j = 8*lk .. 8*lk+7]
    short8v pa = *(const short8v*)&pbw[lr*20 + 4*lk];
    {
      short8v vf0 = *(const short8v*)(vtb + voff);
      short8v vf1 = *(const short8v*)(vtb + voff + 16*S_LEN);
      oaccT0 = mfma16(vf0, pa, oaccT0);
      oaccT1 = mfma16(vf1, pa, oaccT1);
    }
    {
      short8v vf2 = *(const short8v*)(vtb + voff + 32*S_LEN);
      short8v vf3 = *(const short8v*)(vtb + voff + 48*S_LEN);
      oaccT2 = mfma16(vf2, pa, oaccT2);
      oaccT3 = mfma16(vf3, pa, oaccT3);
    }
    voff += 32;
  }

  // epilogue: O^T frag -> O[i=i0+lr][d = nt*16 + lk*4 + r], split bf16,
  // packed 4-wide (8B) stores.
  unsigned short* phi = jh ? p1hi : p0hi;
  unsigned short* plo = jh ? p1lo : p0lo;
  const size_t rowb = (size_t)(b*S_LEN + i0 + lr)*DM + h*HDIM + lk*4;
  float oa[4][4] = {
    {oaccT0[0],oaccT0[1],oaccT0[2],oaccT0[3]},
    {oaccT1[0],oaccT1[1],oaccT1[2],oaccT1[3]},
    {oaccT2[0],oaccT2[1],oaccT2[2],oaccT2[3]},
    {oaccT3[0],oaccT3[1],oaccT3[2],oaccT3[3]}};
#pragma unroll
  for (int nt=0;nt<4;++nt){
    ushort4v hh, ll;
#pragma unroll
    for (int r=0;r<4;++r){
      float vv = oa[nt][r];
      unsigned short hb = bf16_rne(vv);
      hh[r] = hb;
      ll[r] = bf16_rne(vv - bf16_f32(hb));
    }
    *(ushort4v*)(phi + rowb + nt*16) = hh;
    *(ushort4v*)(plo + rowb + nt*16) = ll;
  }
}

// ---------------- combine partial O halves -> split bf16 into (oh,ol) --------
__global__ __launch_bounds__(256) void k_combine(
    const unsigned short* __restrict__ h1, const unsigned short* __restrict__ l1,
    unsigned short* __restrict__ oh, unsigned short* __restrict__ ol, int n8)
{
  int i = blockIdx.x*blockDim.x + threadIdx.x;
  if (i >= n8) return;
  size_t base = (size_t)i*8;
  ushort8v a = *(const ushort8v*)(oh + base);   // jh=0 hi (in place)
  ushort8v bq = *(const ushort8v*)(ol + base);  // jh=0 lo
  ushort8v c = *(const ushort8v*)(h1 + base);
  ushort8v d = *(const ushort8v*)(l1 + base);
  ushort8v rh, rl;
#pragma unroll
  for (int j=0;j<8;++j){
    float f = bf16_f32(a[j]) + bf16_f32(bq[j]) + bf16_f32(c[j]) + bf16_f32(d[j]);
    unsigned short hb = bf16_rne(f);
    rh[j] = hb;
    rl[j] = bf16_rne(f - bf16_f32(hb));
  }
  *(ushort8v*)(oh + base) = rh;
  *(ushort8v*)(ol + base) = rl;
}

// ---------------------------------------------------------------------------
extern "C" void kernel_launch(void* const* d_in, const int* in_sizes, int n_in,
                              void* d_out, int out_size, void* d_ws, size_t ws_size,
                              hipStream_t stream){
  const float* x  = (const float*)d_in[0];
  const float* ts = (const float*)d_in[1];
  const int*   am = (const int*)d_in[2];
  const float* Wq = (const float*)d_in[3];
  const float* bq = (const float*)d_in[4];
  const float* Wk = (const float*)d_in[5];
  const float* bk = (const float*)d_in[6];
  const float* Wv = (const float*)d_in[7];
  const float* bv = (const float*)d_in[8];
  const float* Wo = (const float*)d_in[9];
  const float* bo = (const float*)d_in[10];
  const float* dl = (const float*)d_in[11];

  char* ws = (char*)d_ws;
  unsigned short* xhi = (unsigned short*)(ws);               // x-split; later partial/final opre hi
  unsigned short* xlo = (unsigned short*)(ws + 8388608ull);  // x-split; later partial/final opre lo
  unsigned short* wqt_hi = (unsigned short*)(ws + 16777216ull + 0ull*524288ull);
  unsigned short* wqt_lo = (unsigned short*)(ws + 16777216ull + 1ull*524288ull);
  unsigned short* wkt_hi = (unsigned short*)(ws + 16777216ull + 2ull*524288ull);
  unsigned short* wkt_lo = (unsigned short*)(ws + 16777216ull + 3ull*524288ull);
  unsigned short* wvt_hi = (unsigned short*)(ws + 16777216ull + 4ull*524288ull);
  unsigned short* wvt_lo = (unsigned short*)(ws + 16777216ull + 5ull*524288ull);
  unsigned short* wot_hi = (unsigned short*)(ws + 16777216ull + 6ull*524288ull);
  unsigned short* wot_lo = (unsigned short*)(ws + 16777216ull + 7ull*524288ull);
  unsigned short* qhi = (unsigned short*)(ws + 20971520ull + 0ull*8388608ull);
  unsigned short* qlo = (unsigned short*)(ws + 20971520ull + 1ull*8388608ull);
  unsigned short* khi = (unsigned short*)(ws + 20971520ull + 2ull*8388608ull);
  unsigned short* klo = (unsigned short*)(ws + 20971520ull + 3ull*8388608ull);
  unsigned short* vv  = (unsigned short*)(ws + 20971520ull + 4ull*8388608ull);
  unsigned short* vt  = (unsigned short*)(ws + 20971520ull + 5ull*8388608ull);
  // rs_part reuses the retired Wq slot (free after the q GEMM): 512 KB
  float* rs_part = (float*)(ws + 16777216ull);

  float* outp  = (float*)d_out;
  float* attnp = outp + (size_t)BSROWS*DM;
  // jh=1 partial O stashed in the out0 region (scratch until final GEMM)
  unsigned short* p1hi = (unsigned short*)d_out;
  unsigned short* p1lo = p1hi + 4194304ull;

  k_split<<<4096, 256, 0, stream>>>(x, xhi, xlo, BSROWS*DM);
  k_wsplit<<<1024, 256, 0, stream>>>(Wq, wqt_hi, wqt_lo);
  k_wsplit<<<1024, 256, 0, stream>>>(Wk, wkt_hi, wkt_lo);
  k_wsplit<<<1024, 256, 0, stream>>>(Wv, wvt_hi, wvt_lo);
  k_wsplit<<<1024, 256, 0, stream>>>(Wo, wot_hi, wot_lo);

  dim3 pg(DM/64, BSROWS/128);
  // q pre-scaled by hd^-0.5 * log2(e)
  k_gemm_split<<<pg, 256, 0, stream>>>(xhi, xlo, wqt_hi, wqt_lo, bq,
                                       nullptr, qhi, qlo, BSROWS, DM, DM, 0,
                                       0.18033688f);
  k_gemm_split<<<pg, 256, 0, stream>>>(xhi, xlo, wkt_hi, wkt_lo, bk,
                                       nullptr, khi, klo, BSROWS, DM, DM, 0, 1.f);
  k_gemm_split<<<pg, 256, 0, stream>>>(xhi, xlo, wvt_hi, wvt_lo, bv,
                                       nullptr, vv, nullptr, BSROWS, DM, DM, 1, 1.f);
  k_transpose_v<<<dim3(S_LEN/64, BHN), 256, 0, stream>>>(vv, vt);

  k_rowsum<<<2048, 256, 0, stream>>>(qhi, khi, ts, am, dl, rs_part);
  k_pass2<<<2048, 256, 0, stream>>>(qhi, qlo, khi, klo, vt, ts, am, dl,
                                    rs_part, attnp, xhi, xlo, p1hi, p1lo);
  k_combine<<<2048, 256, 0, stream>>>(p1hi, p1lo, xhi, xlo, 524288);
  k_gemm_split<<<pg, 256, 0, stream>>>(xhi, xlo, wot_hi, wot_lo, bo,
                                       outp, nullptr, nullptr, BSROWS, DM, DM, 2, 1.f);

  (void)in_sizes; (void)n_in; (void)out_size; (void)ws_size;
}

// Round 6
// 752.011 us; speedup vs baseline: 1.2800x; 1.0062x over previous
//
#include <hip/hip_runtime.h>

// ---------------------------------------------------------------------------
// AdaptiveTemporalAttention — MI355X gfx950
// B=4, S=2048, D=512, H=8, hd=64.
// Outputs: out (B,S,D) f32 then attn (B,H,S,S) f32, concatenated in d_out.
//
// Round 6: break the store-ack dependency chain in k_pass2. Theory: VMEM
// stores hold their data VGPRs until retirement; with minimal regalloc the
// pv registers are reused next subtile -> every subtile waits on the
// previous attn-store's L2 ack (~400-800 cyc) = the ~85% stall seen in
// R1-R5. Fix: defer the attn store one full iteration via explicitly-live
// sv0/sv1 rotation registers (compiler can't merge two live regs), plus
// explicit 1-subtile K prefetch + hoisted vT loads now that the store
// chain is broken. Everything else identical to round 5.
// ---------------------------------------------------------------------------

#define S_LEN  2048
#define DM     512
#define NH     8
#define HDIM   64
#define BATCH  4
#define BHN    32     // BATCH*NH
#define BSROWS 8192   // BATCH*S_LEN

typedef __attribute__((ext_vector_type(8))) short short8v;
typedef __attribute__((ext_vector_type(8))) unsigned short ushort8v;
typedef __attribute__((ext_vector_type(4))) unsigned short ushort4v;
typedef __attribute__((ext_vector_type(4))) float f32x4;
typedef __attribute__((ext_vector_type(2))) unsigned int uint2v;

static __device__ __forceinline__ unsigned short bf16_rne(float f){
  unsigned int u = __float_as_uint(f);
  u = (u + 0x7FFFu + ((u >> 16) & 1u)) >> 16;
  return (unsigned short)u;
}
static __device__ __forceinline__ float bf16_f32(unsigned short h){
  return __uint_as_float(((unsigned int)h) << 16);
}
static __device__ __forceinline__ unsigned int pack2bf(float a, float b){
  return (unsigned int)bf16_rne(a) | ((unsigned int)bf16_rne(b) << 16);
}
static __device__ __forceinline__ f32x4 mfma16(short8v a, short8v b, f32x4 c){
  return __builtin_amdgcn_mfma_f32_16x16x32_bf16(a, b, c, 0, 0, 0);
}

// ---------------- prep: elementwise split f32 -> (hi,lo) bf16 ----------------
__global__ void k_split(const float* __restrict__ src,
                        unsigned short* __restrict__ hi,
                        unsigned short* __restrict__ lo, int n){
  for (int i = blockIdx.x*blockDim.x + threadIdx.x; i < n;
       i += gridDim.x*blockDim.x){
    float f = src[i];
    unsigned short h = bf16_rne(f);
    hi[i] = h;
    lo[i] = bf16_rne(f - bf16_f32(h));
  }
}

// ---------------- prep: transpose 512x512 W -> WT, split ----------------
__global__ void k_wsplit(const float* __restrict__ W,
                         unsigned short* __restrict__ Thi,
                         unsigned short* __restrict__ Tlo){
  int idx = blockIdx.x*blockDim.x + threadIdx.x; // (n,k) with k fastest
  int n = idx >> 9, k = idx & 511;
  float f = W[k*DM + n];
  unsigned short h = bf16_rne(f);
  Thi[idx] = h;
  Tlo[idx] = bf16_rne(f - bf16_f32(h));
}

// ---------------- split-precision GEMM: C = (A@B + bias)*cscale ----------------
__global__ __launch_bounds__(256) void k_gemm_split(
    const unsigned short* __restrict__ Ahi, const unsigned short* __restrict__ Alo,
    const unsigned short* __restrict__ BThi, const unsigned short* __restrict__ BTlo,
    const float* __restrict__ bias,
    float* __restrict__ outF,
    unsigned short* __restrict__ outHi, unsigned short* __restrict__ outLo,
    int M, int N, int K, int mode, float cscale)
{
  const int lane = threadIdx.x & 63, w = threadIdx.x >> 6;
  const int lr = lane & 15, lk = lane >> 4;
  const int rowbase = blockIdx.y*128 + (w >> 1)*64;
  const int colbase = blockIdx.x*64  + (w & 1)*32;

  f32x4 acc[4][2];
#pragma unroll
  for (int mi=0; mi<4; ++mi)
#pragma unroll
    for (int ni=0; ni<2; ++ni) acc[mi][ni] = (f32x4){0.f,0.f,0.f,0.f};

  for (int k0 = 0; k0 < K; k0 += 32){
    short8v ah[4], al[4], bh[2], bl[2];
#pragma unroll
    for (int mi=0; mi<4; ++mi){
      size_t off = (size_t)(rowbase + mi*16 + lr)*K + k0 + lk*8;
      ah[mi] = *(const short8v*)(Ahi + off);
      al[mi] = *(const short8v*)(Alo + off);
    }
#pragma unroll
    for (int ni=0; ni<2; ++ni){
      size_t off = (size_t)(colbase + ni*16 + lr)*K + k0 + lk*8;
      bh[ni] = *(const short8v*)(BThi + off);
      bl[ni] = *(const short8v*)(BTlo + off);
    }
#pragma unroll
    for (int mi=0; mi<4; ++mi)
#pragma unroll
      for (int ni=0; ni<2; ++ni){
        acc[mi][ni] = mfma16(ah[mi], bl[ni], acc[mi][ni]);
        acc[mi][ni] = mfma16(al[mi], bh[ni], acc[mi][ni]);
        acc[mi][ni] = mfma16(ah[mi], bh[ni], acc[mi][ni]);
      }
  }

#pragma unroll
  for (int mi=0; mi<4; ++mi)
#pragma unroll
    for (int ni=0; ni<2; ++ni)
#pragma unroll
      for (int r=0; r<4; ++r){
        int row = rowbase + mi*16 + lk*4 + r;   // C/D frag: row=(lane>>4)*4+r
        int col = colbase + ni*16 + lr;         //           col=lane&15
        float c = (acc[mi][ni][r] + bias[col]) * cscale;
        if (mode == 2){
          outF[(size_t)row*N + col] = c;
        } else {
          int b = row >> 11, s = row & 2047, hh = col >> 6, d = col & 63;
          size_t off = (((size_t)(b*NH + hh))*S_LEN + s)*HDIM + d;
          unsigned short hb = bf16_rne(c);
          outHi[off] = hb;
          if (mode == 0) outLo[off] = bf16_rne(c - bf16_f32(hb));
        }
      }
}

// ---------------- v [bh][s][d] -> vT [bh][d][s] ----------------
__global__ __launch_bounds__(256) void k_transpose_v(
    const unsigned short* __restrict__ v, unsigned short* __restrict__ vT){
  __shared__ __align__(16) unsigned short tile[64][72];
  const int bh = blockIdx.y, st = blockIdx.x;
  const int r = threadIdx.x >> 2, seg = threadIdx.x & 3;
  const unsigned short* src = v + ((size_t)bh*S_LEN + st*64 + r)*HDIM + seg*16;
  *(ushort8v*)&tile[r][seg*16]     = *(const ushort8v*)(src);
  *(ushort8v*)&tile[r][seg*16 + 8] = *(const ushort8v*)(src + 8);
  __syncthreads();
  __align__(16) unsigned short tmp[16];
#pragma unroll
  for (int i=0;i<16;++i) tmp[i] = tile[seg*16 + i][r];
  unsigned short* dst = vT + ((size_t)bh*HDIM + r)*S_LEN + st*64 + seg*16;
  *(ushort8v*)(dst)     = *(const ushort8v*)&tmp[0];
  *(ushort8v*)(dst + 8) = *(const ushort8v*)&tmp[8];
}

// ---------------- rowsum kernel (swapped: S^T = mfma(K, Q), hi-only) ---------
__global__ __launch_bounds__(256) void k_rowsum(
    const unsigned short* __restrict__ qhi,
    const unsigned short* __restrict__ khi,
    const float* __restrict__ ts, const int* __restrict__ am,
    const float* __restrict__ dlam,
    float* __restrict__ rs_part)
{
  __shared__ __align__(16) float ts_l[1024];
  __shared__ __align__(16) float mb_l[1024];
  const int w = threadIdx.x >> 6, lane = threadIdx.x & 63;
  const int lr = lane & 15, lk = lane >> 4;
  const int wg = blockIdx.x;
  const int sw = (wg & 7)*256 + (wg >> 3);
  const int bh = sw >> 6, rem = sw & 63, it = rem >> 1, jh = rem & 1;
  const int b = bh >> 3, h = bh & 7;
  const int i0 = it*64 + w*16;
  const int j0 = jh*1024;

  const float* tsb = ts + b*S_LEN;
  const int*   amb = am + b*S_LEN;
  for (int i = threadIdx.x; i < 1024; i += 256){
    ts_l[i] = tsb[j0+i];
    mb_l[i] = amb[j0+i] ? 0.f : -1e30f;
  }

  float nlam2 = -log1pf(expf(dlam[h])) * 1.44269504f;
  nlam2 = __uint_as_float(__builtin_amdgcn_readfirstlane(__float_as_uint(nlam2)));

  size_t qoff = ((size_t)bh*S_LEN + i0 + lr)*HDIM + lk*8;
  const short8v qh0 = *(const short8v*)(qhi + qoff);
  const short8v qh1 = *(const short8v*)(qhi + qoff + 32);
  const float ti = tsb[i0 + lr];

  const unsigned short* kb = khi + ((size_t)bh*S_LEN + j0)*HDIM;
  __syncthreads();

  float rs = 0.f;
  int koff = lr*HDIM + lk*8;
  for (int jt = 0; jt < 64; jt += 2){
    short8v a0 = *(const short8v*)(kb + koff);
    short8v a1 = *(const short8v*)(kb + koff + 32);
    short8v c0 = *(const short8v*)(kb + koff + 1024);
    short8v c1 = *(const short8v*)(kb + koff + 1024 + 32);
    f32x4 sA = (f32x4){0.f,0.f,0.f,0.f};
    sA = mfma16(a0, qh0, sA);
    sA = mfma16(a1, qh1, sA);
    f32x4 sB = (f32x4){0.f,0.f,0.f,0.f};
    sB = mfma16(c0, qh0, sB);
    sB = mfma16(c1, qh1, sB);
    f32x4 tsA = *(const f32x4*)&ts_l[jt*16 + lk*4];
    f32x4 mbA = *(const f32x4*)&mb_l[jt*16 + lk*4];
    f32x4 tsB = *(const f32x4*)&ts_l[jt*16 + 16 + lk*4];
    f32x4 mbB = *(const f32x4*)&mb_l[jt*16 + 16 + lk*4];
#pragma unroll
    for (int r=0;r<4;++r){
      float decA = __builtin_amdgcn_exp2f(nlam2 * fabsf(ti - tsA[r]));
      rs += __builtin_amdgcn_exp2f(__builtin_fmaf(sA[r], decA, mbA[r]));
      float decB = __builtin_amdgcn_exp2f(nlam2 * fabsf(ti - tsB[r]));
      rs += __builtin_amdgcn_exp2f(__builtin_fmaf(sB[r], decB, mbB[r]));
    }
    koff += 2048;
  }
  rs += __shfl_xor(rs, 16, 64);
  rs += __shfl_xor(rs, 32, 64);
  if (lane < 16)
    rs_part[(size_t)(jh*BHN + bh)*S_LEN + i0 + lane] = rs;
}

// ---------------- pass-2: attn write (deferred-store rotation) + PV ----------
// grid 2048 = (bh x i-tile x j-half), 256 thr = 4 waves x 16 rows.
// Swapped QK: lane (lr,lk) owns row i=i0+lr, j = jt*16+lk*4+r.
// Store rotation: sv0/sv1 hold the previous iteration's pv; stored at the
// TOP of the next iteration so the overwrite-wait lands ~700+ cyc after
// store issue (ack hidden). Explicit 1-subtile K prefetch (nk*), vT loads
// hoisted to iteration top.
__global__ __launch_bounds__(256, 4) void k_pass2(
    const unsigned short* __restrict__ qhi, const unsigned short* __restrict__ qlo,
    const unsigned short* __restrict__ khi, const unsigned short* __restrict__ klo,
    const unsigned short* __restrict__ vT,
    const float* __restrict__ ts, const int* __restrict__ am,
    const float* __restrict__ dlam,
    const float* __restrict__ rs_part,
    float* __restrict__ attn,
    unsigned short* __restrict__ p0hi, unsigned short* __restrict__ p0lo,
    unsigned short* __restrict__ p1hi, unsigned short* __restrict__ p1lo)
{
  __shared__ __align__(16) float ts_l[1024];
  __shared__ __align__(16) float mb_l[1024];
  __shared__ __align__(16) unsigned int pb[4][16][20];  // [wave][i-row][pad 20]
  const int w = threadIdx.x >> 6, lane = threadIdx.x & 63;
  const int lr = lane & 15, lk = lane >> 4;
  const int wg = blockIdx.x;
  const int sw = (wg & 7)*256 + (wg >> 3);
  const int bh = sw >> 6, rem = sw & 63, it = rem >> 1, jh = rem & 1;
  const int b = bh >> 3, h = bh & 7;
  const int i0 = it*64 + w*16;
  const int j0 = jh*1024;

  const float* tsb = ts + b*S_LEN;
  const int*   amb = am + b*S_LEN;
  for (int i = threadIdx.x; i < 1024; i += 256){
    ts_l[i] = tsb[j0+i];
    mb_l[i] = amb[j0+i] ? 0.f : -1e30f;
  }

  float nlam2 = -log1pf(expf(dlam[h])) * 1.44269504f;
  nlam2 = __uint_as_float(__builtin_amdgcn_readfirstlane(__float_as_uint(nlam2)));

  size_t qoff = ((size_t)bh*S_LEN + i0 + lr)*HDIM + lk*8;
  const short8v qh0 = *(const short8v*)(qhi + qoff);
  const short8v qh1 = *(const short8v*)(qhi + qoff + 32);
  const short8v ql0 = *(const short8v*)(qlo + qoff);
  const short8v ql1 = *(const short8v*)(qlo + qoff + 32);
  const float ti = tsb[i0 + lr];

  float tot = rs_part[(size_t)bh*S_LEN + i0 + lr]
            + rs_part[(size_t)(BHN + bh)*S_LEN + i0 + lr];
  const float rinv = tot > 0.f ? 1.f/tot : 0.f;

  const unsigned short* kbh = khi + ((size_t)bh*S_LEN + j0)*HDIM;
  const unsigned short* kbl = klo + ((size_t)bh*S_LEN + j0)*HDIM;
  const unsigned short* vtb = vT + (size_t)bh*HDIM*S_LEN;
  unsigned int* pbw = &pb[w][0][0];

  const unsigned int abase = (unsigned int)(bh*S_LEN + i0 + lr)*S_LEN + j0;

  __syncthreads();

  f32x4 oaccT0 = (f32x4){0.f,0.f,0.f,0.f};
  f32x4 oaccT1 = (f32x4){0.f,0.f,0.f,0.f};
  f32x4 oaccT2 = (f32x4){0.f,0.f,0.f,0.f};
  f32x4 oaccT3 = (f32x4){0.f,0.f,0.f,0.f};

  // deferred-store rotation registers (prev iteration's pv for halves 0/1)
  f32x4 sv0, sv1;
  // K prefetch registers: subtile 0 loaded before the loop
  int koff = lr*HDIM + lk*8;
  short8v nkh0 = *(const short8v*)(kbh + koff);
  short8v nkh1 = *(const short8v*)(kbh + koff + 32);
  short8v nkl0 = *(const short8v*)(kbl + koff);
  short8v nkl1 = *(const short8v*)(kbl + koff + 32);
  koff += 1024;

  int voff = lr*S_LEN + j0 + lk*8;
  for (int jt = 0; jt < 64; jt += 2){
    // 1) store PREVIOUS iteration's pv (ack will be waited on ~2 subtiles later)
    if (jt){
      *(f32x4*)(attn + abase + (jt-2)*16 + lk*4) = sv0;
      *(f32x4*)(attn + abase + (jt-1)*16 + lk*4) = sv1;
    }
    // 2) hoisted vT loads for this iteration's PV
    short8v vf0 = *(const short8v*)(vtb + voff);
    short8v vf1 = *(const short8v*)(vtb + voff + 16*S_LEN);
    short8v vf2 = *(const short8v*)(vtb + voff + 32*S_LEN);
    short8v vf3 = *(const short8v*)(vtb + voff + 48*S_LEN);
#pragma unroll
    for (int half=0; half<2; ++half){
      // consume prefetched K, immediately prefetch next subtile
      short8v kh0 = nkh0, kh1 = nkh1, kl0 = nkl0, kl1 = nkl1;
      nkh0 = *(const short8v*)(kbh + koff);
      nkh1 = *(const short8v*)(kbh + koff + 32);
      nkl0 = *(const short8v*)(kbl + koff);
      nkl1 = *(const short8v*)(kbl + koff + 32);
      koff += 1024;
      // swapped QK: split accumulators (4-chain corrections + 2-chain hi)
      f32x4 s1 = (f32x4){0.f,0.f,0.f,0.f};
      s1 = mfma16(kh0, ql0, s1);
      s1 = mfma16(kl0, qh0, s1);
      s1 = mfma16(kh1, ql1, s1);
      s1 = mfma16(kl1, qh1, s1);
      f32x4 s2 = (f32x4){0.f,0.f,0.f,0.f};
      s2 = mfma16(kh0, qh0, s2);
      s2 = mfma16(kh1, qh1, s2);
      const int jb = (jt+half)*16 + lk*4;
      f32x4 ts4 = *(const f32x4*)&ts_l[jb];
      f32x4 mb4 = *(const f32x4*)&mb_l[jb];
      f32x4 pv;
#pragma unroll
      for (int r=0;r<4;++r){
        float sa = s1[r] + s2[r];
        float dec = __builtin_amdgcn_exp2f(nlam2 * fabsf(ti - ts4[r]));
        float e = __builtin_amdgcn_exp2f(__builtin_fmaf(sa, dec, mb4[r]));
        pv[r] = e * rinv;
      }
      if (half == 0) sv0 = pv; else sv1 = pv;
      // stage packed bf16 pairs for PV: row lr, u32 cols {half*8 + 2lk, +1}
      uint2v pk; pk.x = pack2bf(pv[0], pv[1]); pk.y = pack2bf(pv[2], pv[3]);
      *(uint2v*)&pbw[lr*20 + half*8 + 2*lk] = pk;
    }
    // PV for this 32-j chunk: pa = P[i=lr][j = 8*lk .. 8*lk+7]
    short8v pa = *(const short8v*)&pbw[lr*20 + 4*lk];
    oaccT0 = mfma16(vf0, pa, oaccT0);
    oaccT1 = mfma16(vf1, pa, oaccT1);
    oaccT2 = mfma16(vf2, pa, oaccT2);
    oaccT3 = mfma16(vf3, pa, oaccT3);
    voff += 32;
  }
  // drain the last iteration's deferred stores
  *(f32x4*)(attn + abase + 62*16 + lk*4) = sv0;
  *(f32x4*)(attn + abase + 63*16 + lk*4) = sv1;

  // epilogue: O^T frag -> O[i=i0+lr][d = nt*16 + lk*4 + r], split bf16
  unsigned short* phi = jh ? p1hi : p0hi;
  unsigned short* plo = jh ? p1lo : p0lo;
  const size_t rowb = (size_t)(b*S_LEN + i0 + lr)*DM + h*HDIM + lk*4;
  float oa[4][4] = {
    {oaccT0[0],oaccT0[1],oaccT0[2],oaccT0[3]},
    {oaccT1[0],oaccT1[1],oaccT1[2],oaccT1[3]},
    {oaccT2[0],oaccT2[1],oaccT2[2],oaccT2[3]},
    {oaccT3[0],oaccT3[1],oaccT3[2],oaccT3[3]}};
#pragma unroll
  for (int nt=0;nt<4;++nt){
    ushort4v hh, ll;
#pragma unroll
    for (int r=0;r<4;++r){
      float vv = oa[nt][r];
      unsigned short hb = bf16_rne(vv);
      hh[r] = hb;
      ll[r] = bf16_rne(vv - bf16_f32(hb));
    }
    *(ushort4v*)(phi + rowb + nt*16) = hh;
    *(ushort4v*)(plo + rowb + nt*16) = ll;
  }
}

// ---------------- combine partial O halves -> split bf16 into (oh,ol) --------
__global__ __launch_bounds__(256) void k_combine(
    const unsigned short* __restrict__ h1, const unsigned short* __restrict__ l1,
    unsigned short* __restrict__ oh, unsigned short* __restrict__ ol, int n8)
{
  int i = blockIdx.x*blockDim.x + threadIdx.x;
  if (i >= n8) return;
  size_t base = (size_t)i*8;
  ushort8v a = *(const ushort8v*)(oh + base);   // jh=0 hi (in place)
  ushort8v bq = *(const ushort8v*)(ol + base);  // jh=0 lo
  ushort8v c = *(const ushort8v*)(h1 + base);
  ushort8v d = *(const ushort8v*)(l1 + base);
  ushort8v rh, rl;
#pragma unroll
  for (int j=0;j<8;++j){
    float f = bf16_f32(a[j]) + bf16_f32(bq[j]) + bf16_f32(c[j]) + bf16_f32(d[j]);
    unsigned short hb = bf16_rne(f);
    rh[j] = hb;
    rl[j] = bf16_rne(f - bf16_f32(hb));
  }
  *(ushort8v*)(oh + base) = rh;
  *(ushort8v*)(ol + base) = rl;
}

// ---------------------------------------------------------------------------
extern "C" void kernel_launch(void* const* d_in, const int* in_sizes, int n_in,
                              void* d_out, int out_size, void* d_ws, size_t ws_size,
                              hipStream_t stream){
  const float* x  = (const float*)d_in[0];
  const float* ts = (const float*)d_in[1];
  const int*   am = (const int*)d_in[2];
  const float* Wq = (const float*)d_in[3];
  const float* bq = (const float*)d_in[4];
  const float* Wk = (const float*)d_in[5];
  const float* bk = (const float*)d_in[6];
  const float* Wv = (const float*)d_in[7];
  const float* bv = (const float*)d_in[8];
  const float* Wo = (const float*)d_in[9];
  const float* bo = (const float*)d_in[10];
  const float* dl = (const float*)d_in[11];

  char* ws = (char*)d_ws;
  unsigned short* xhi = (unsigned short*)(ws);               // x-split; later final opre hi
  unsigned short* xlo = (unsigned short*)(ws + 8388608ull);  // x-split; later final opre lo
  unsigned short* wqt_hi = (unsigned short*)(ws + 16777216ull + 0ull*524288ull);
  unsigned short* wqt_lo = (unsigned short*)(ws + 16777216ull + 1ull*524288ull);
  unsigned short* wkt_hi = (unsigned short*)(ws + 16777216ull + 2ull*524288ull);
  unsigned short* wkt_lo = (unsigned short*)(ws + 16777216ull + 3ull*524288ull);
  unsigned short* wvt_hi = (unsigned short*)(ws + 16777216ull + 4ull*524288ull);
  unsigned short* wvt_lo = (unsigned short*)(ws + 16777216ull + 5ull*524288ull);
  unsigned short* wot_hi = (unsigned short*)(ws + 16777216ull + 6ull*524288ull);
  unsigned short* wot_lo = (unsigned short*)(ws + 16777216ull + 7ull*524288ull);
  unsigned short* qhi = (unsigned short*)(ws + 20971520ull + 0ull*8388608ull);
  unsigned short* qlo = (unsigned short*)(ws + 20971520ull + 1ull*8388608ull);
  unsigned short* khi = (unsigned short*)(ws + 20971520ull + 2ull*8388608ull);
  unsigned short* klo = (unsigned short*)(ws + 20971520ull + 3ull*8388608ull);
  unsigned short* vv  = (unsigned short*)(ws + 20971520ull + 4ull*8388608ull);
  unsigned short* vt  = (unsigned short*)(ws + 20971520ull + 5ull*8388608ull);
  // rs_part reuses the retired Wq slot (free after the q GEMM): 512 KB
  float* rs_part = (float*)(ws + 16777216ull);

  float* outp  = (float*)d_out;
  float* attnp = outp + (size_t)BSROWS*DM;
  // jh=1 partial O stashed in the out0 region (scratch until final GEMM)
  unsigned short* p1hi = (unsigned short*)d_out;
  unsigned short* p1lo = p1hi + 4194304ull;

  k_split<<<4096, 256, 0, stream>>>(x, xhi, xlo, BSROWS*DM);
  k_wsplit<<<1024, 256, 0, stream>>>(Wq, wqt_hi, wqt_lo);
  k_wsplit<<<1024, 256, 0, stream>>>(Wk, wkt_hi, wkt_lo);
  k_wsplit<<<1024, 256, 0, stream>>>(Wv, wvt_hi, wvt_lo);
  k_wsplit<<<1024, 256, 0, stream>>>(Wo, wot_hi, wot_lo);

  dim3 pg(DM/64, BSROWS/128);
  // q pre-scaled by hd^-0.5 * log2(e)
  k_gemm_split<<<pg, 256, 0, stream>>>(xhi, xlo, wqt_hi, wqt_lo, bq,
                                       nullptr, qhi, qlo, BSROWS, DM, DM, 0,
                                       0.18033688f);
  k_gemm_split<<<pg, 256, 0, stream>>>(xhi, xlo, wkt_hi, wkt_lo, bk,
                                       nullptr, khi, klo, BSROWS, DM, DM, 0, 1.f);
  k_gemm_split<<<pg, 256, 0, stream>>>(xhi, xlo, wvt_hi, wvt_lo, bv,
                                       nullptr, vv, nullptr, BSROWS, DM, DM, 1, 1.f);
  k_transpose_v<<<dim3(S_LEN/64, BHN), 256, 0, stream>>>(vv, vt);

  k_rowsum<<<2048, 256, 0, stream>>>(qhi, khi, ts, am, dl, rs_part);
  k_pass2<<<2048, 256, 0, stream>>>(qhi, qlo, khi, klo, vt, ts, am, dl,
                                    rs_part, attnp, xhi, xlo, p1hi, p1lo);
  k_combine<<<2048, 256, 0, stream>>>(p1hi, p1lo, xhi, xlo, 524288);
  k_gemm_split<<<pg, 256, 0, stream>>>(xhi, xlo, wot_hi, wot_lo, bo,
                                       outp, nullptr, nullptr, BSROWS, DM, DM, 2, 1.f);

  (void)in_sizes; (void)n_in; (void)out_size; (void)ws_size;
}

// Round 7
// 504.449 us; speedup vs baseline: 1.9081x; 1.4908x over previous
//
#include <hip/hip_runtime.h>

// ---------------------------------------------------------------------------
// AdaptiveTemporalAttention — MI355X gfx950
// B=4, S=2048, D=512, H=8, hd=64.
// Outputs: out (B,S,D) f32 then attn (B,H,S,S) f32, concatenated in d_out.
//
// Round 7: LDS-stage K and vT (global_load_lds dwordx4, double-buffered,
// 1 barrier/iter) in k_pass2/k_rowsum. R1-R6 established the stall is the
// per-CU VMEM request stream: every load/store was a 16-segment gather and
// all 4 waves of a block loaded IDENTICAL K/vT (4x redundancy, L1 too small).
// Staging cuts VMEM instrs ~14x and L2 demand 4x; frag reads become
// conflict-free ds_read_b128 via XOR-swizzle (G21: linear LDS dest +
// inverse-swizzled global source + swizzled read).
//   K tile [32][128B]: c16 ^= (row&7)   -> 2 lanes/bank (free)
//   V tile [64][64B] : c16 ^= ((d>>2)&3)-> 2 lanes/bank (free)
// ---------------------------------------------------------------------------

#define S_LEN  2048
#define DM     512
#define NH     8
#define HDIM   64
#define BATCH  4
#define BHN    32     // BATCH*NH
#define BSROWS 8192   // BATCH*S_LEN

typedef __attribute__((ext_vector_type(8))) short short8v;
typedef __attribute__((ext_vector_type(8))) unsigned short ushort8v;
typedef __attribute__((ext_vector_type(4))) unsigned short ushort4v;
typedef __attribute__((ext_vector_type(4))) float f32x4;
typedef __attribute__((ext_vector_type(2))) unsigned int uint2v;

static __device__ __forceinline__ unsigned short bf16_rne(float f){
  unsigned int u = __float_as_uint(f);
  u = (u + 0x7FFFu + ((u >> 16) & 1u)) >> 16;
  return (unsigned short)u;
}
static __device__ __forceinline__ float bf16_f32(unsigned short h){
  return __uint_as_float(((unsigned int)h) << 16);
}
static __device__ __forceinline__ unsigned int pack2bf(float a, float b){
  return (unsigned int)bf16_rne(a) | ((unsigned int)bf16_rne(b) << 16);
}
static __device__ __forceinline__ f32x4 mfma16(short8v a, short8v b, f32x4 c){
  return __builtin_amdgcn_mfma_f32_16x16x32_bf16(a, b, c, 0, 0, 0);
}
// async global->LDS, 16B per lane; dst must be wave-uniform (lane*16 appended by HW)
static __device__ __forceinline__ void gll16(const unsigned short* g, unsigned short* l){
  __builtin_amdgcn_global_load_lds(
      (const __attribute__((address_space(1))) unsigned int*)g,
      (__attribute__((address_space(3))) unsigned int*)l, 16, 0, 0);
}

// ---------------- prep: elementwise split f32 -> (hi,lo) bf16 ----------------
__global__ void k_split(const float* __restrict__ src,
                        unsigned short* __restrict__ hi,
                        unsigned short* __restrict__ lo, int n){
  for (int i = blockIdx.x*blockDim.x + threadIdx.x; i < n;
       i += gridDim.x*blockDim.x){
    float f = src[i];
    unsigned short h = bf16_rne(f);
    hi[i] = h;
    lo[i] = bf16_rne(f - bf16_f32(h));
  }
}

// ---------------- prep: transpose 512x512 W -> WT, split ----------------
__global__ void k_wsplit(const float* __restrict__ W,
                         unsigned short* __restrict__ Thi,
                         unsigned short* __restrict__ Tlo){
  int idx = blockIdx.x*blockDim.x + threadIdx.x; // (n,k) with k fastest
  int n = idx >> 9, k = idx & 511;
  float f = W[k*DM + n];
  unsigned short h = bf16_rne(f);
  Thi[idx] = h;
  Tlo[idx] = bf16_rne(f - bf16_f32(h));
}

// ---------------- split-precision GEMM: C = (A@B + bias)*cscale ----------------
__global__ __launch_bounds__(256) void k_gemm_split(
    const unsigned short* __restrict__ Ahi, const unsigned short* __restrict__ Alo,
    const unsigned short* __restrict__ BThi, const unsigned short* __restrict__ BTlo,
    const float* __restrict__ bias,
    float* __restrict__ outF,
    unsigned short* __restrict__ outHi, unsigned short* __restrict__ outLo,
    int M, int N, int K, int mode, float cscale)
{
  const int lane = threadIdx.x & 63, w = threadIdx.x >> 6;
  const int lr = lane & 15, lk = lane >> 4;
  const int rowbase = blockIdx.y*128 + (w >> 1)*64;
  const int colbase = blockIdx.x*64  + (w & 1)*32;

  f32x4 acc[4][2];
#pragma unroll
  for (int mi=0; mi<4; ++mi)
#pragma unroll
    for (int ni=0; ni<2; ++ni) acc[mi][ni] = (f32x4){0.f,0.f,0.f,0.f};

  for (int k0 = 0; k0 < K; k0 += 32){
    short8v ah[4], al[4], bh[2], bl[2];
#pragma unroll
    for (int mi=0; mi<4; ++mi){
      size_t off = (size_t)(rowbase + mi*16 + lr)*K + k0 + lk*8;
      ah[mi] = *(const short8v*)(Ahi + off);
      al[mi] = *(const short8v*)(Alo + off);
    }
#pragma unroll
    for (int ni=0; ni<2; ++ni){
      size_t off = (size_t)(colbase + ni*16 + lr)*K + k0 + lk*8;
      bh[ni] = *(const short8v*)(BThi + off);
      bl[ni] = *(const short8v*)(BTlo + off);
    }
#pragma unroll
    for (int mi=0; mi<4; ++mi)
#pragma unroll
      for (int ni=0; ni<2; ++ni){
        acc[mi][ni] = mfma16(ah[mi], bl[ni], acc[mi][ni]);
        acc[mi][ni] = mfma16(al[mi], bh[ni], acc[mi][ni]);
        acc[mi][ni] = mfma16(ah[mi], bh[ni], acc[mi][ni]);
      }
  }

#pragma unroll
  for (int mi=0; mi<4; ++mi)
#pragma unroll
    for (int ni=0; ni<2; ++ni)
#pragma unroll
      for (int r=0; r<4; ++r){
        int row = rowbase + mi*16 + lk*4 + r;   // C/D frag: row=(lane>>4)*4+r
        int col = colbase + ni*16 + lr;         //           col=lane&15
        float c = (acc[mi][ni][r] + bias[col]) * cscale;
        if (mode == 2){
          outF[(size_t)row*N + col] = c;
        } else {
          int b = row >> 11, s = row & 2047, hh = col >> 6, d = col & 63;
          size_t off = (((size_t)(b*NH + hh))*S_LEN + s)*HDIM + d;
          unsigned short hb = bf16_rne(c);
          outHi[off] = hb;
          if (mode == 0) outLo[off] = bf16_rne(c - bf16_f32(hb));
        }
      }
}

// ---------------- v [bh][s][d] -> vT [bh][d][s] ----------------
__global__ __launch_bounds__(256) void k_transpose_v(
    const unsigned short* __restrict__ v, unsigned short* __restrict__ vT){
  __shared__ __align__(16) unsigned short tile[64][72];
  const int bh = blockIdx.y, st = blockIdx.x;
  const int r = threadIdx.x >> 2, seg = threadIdx.x & 3;
  const unsigned short* src = v + ((size_t)bh*S_LEN + st*64 + r)*HDIM + seg*16;
  *(ushort8v*)&tile[r][seg*16]     = *(const ushort8v*)(src);
  *(ushort8v*)&tile[r][seg*16 + 8] = *(const ushort8v*)(src + 8);
  __syncthreads();
  __align__(16) unsigned short tmp[16];
#pragma unroll
  for (int i=0;i<16;++i) tmp[i] = tile[seg*16 + i][r];
  unsigned short* dst = vT + ((size_t)bh*HDIM + r)*S_LEN + st*64 + seg*16;
  *(ushort8v*)(dst)     = *(const ushort8v*)&tmp[0];
  *(ushort8v*)(dst + 8) = *(const ushort8v*)&tmp[8];
}

// ---------------- rowsum kernel (LDS-staged K-hi, swapped QK) ----------------
// grid 2048 = (bh x i-tile x j-half), 256 thr = 4 waves x 16 rows.
__global__ __launch_bounds__(256) void k_rowsum(
    const unsigned short* __restrict__ qhi,
    const unsigned short* __restrict__ khi,
    const float* __restrict__ ts, const int* __restrict__ am,
    const float* __restrict__ dlam,
    float* __restrict__ rs_part)
{
  __shared__ __align__(16) unsigned short K_t[2][32][64];  // [buf][row][128B], swz
  __shared__ __align__(16) float ts_l[1024];
  __shared__ __align__(16) float mb_l[1024];
  const int w = threadIdx.x >> 6, lane = threadIdx.x & 63;
  const int lr = lane & 15, lk = lane >> 4;
  const int wg = blockIdx.x;
  const int sw = (wg & 7)*256 + (wg >> 3);
  const int bh = sw >> 6, rem = sw & 63, it = rem >> 1, jh = rem & 1;
  const int b = bh >> 3, h = bh & 7;
  const int i0 = it*64 + w*16;
  const int j0 = jh*1024;

  const float* tsb = ts + b*S_LEN;
  const int*   amb = am + b*S_LEN;
  for (int i = threadIdx.x; i < 1024; i += 256){
    ts_l[i] = tsb[j0+i];
    mb_l[i] = amb[j0+i] ? 0.f : -1e30f;
  }

  float nlam2 = -log1pf(expf(dlam[h])) * 1.44269504f;
  nlam2 = __uint_as_float(__builtin_amdgcn_readfirstlane(__float_as_uint(nlam2)));

  size_t qoff = ((size_t)bh*S_LEN + i0 + lr)*HDIM + lk*8;
  const short8v qh0 = *(const short8v*)(qhi + qoff);
  const short8v qh1 = *(const short8v*)(qhi + qoff + 32);
  const float ti = tsb[i0 + lr];

  const unsigned short* kbh = khi + ((size_t)bh*S_LEN + j0)*HDIM;
  // per-lane staging source (wave w stages rows w*8..w*8+7 of each 32-row tile)
  const unsigned short* ksrc = kbh + ((lane>>3))*64
                             + (((lane&7)^((lane>>3)&7))*8) + w*512;
  unsigned short* kdst = &K_t[0][0][0] + w*512;        // buf stride 2048 shorts

  gll16(ksrc, kdst);                                   // t=0
  __syncthreads();

  float rs = 0.f;
  for (int t = 0; t < 32; ++t){
    const int c = t & 1;
    if (t < 31) gll16(ksrc + (t+1)*2048, kdst + (c^1)*2048);
#pragma unroll
    for (int s = 0; s < 2; ++s){
      const unsigned short* Kr = &K_t[c][s*16 + lr][0];
      short8v a0 = *(const short8v*)(Kr + ((lk ^ (lr&7))*8));
      short8v a1 = *(const short8v*)(Kr + (((4+lk) ^ (lr&7))*8));
      f32x4 sA = (f32x4){0.f,0.f,0.f,0.f};
      sA = mfma16(a0, qh0, sA);
      sA = mfma16(a1, qh1, sA);
      const int jb = t*32 + s*16 + lk*4;
      f32x4 ts4 = *(const f32x4*)&ts_l[jb];
      f32x4 mb4 = *(const f32x4*)&mb_l[jb];
#pragma unroll
      for (int r=0;r<4;++r){
        float dec = __builtin_amdgcn_exp2f(nlam2 * fabsf(ti - ts4[r]));
        rs += __builtin_amdgcn_exp2f(__builtin_fmaf(sA[r], dec, mb4[r]));
      }
    }
    __syncthreads();
  }
  rs += __shfl_xor(rs, 16, 64);
  rs += __shfl_xor(rs, 32, 64);
  if (lane < 16)
    rs_part[(size_t)(jh*BHN + bh)*S_LEN + i0 + lane] = rs;
}

// ---------------- pass-2: LDS-staged K+vT, attn write + partial PV ----------
// grid 2048 = (bh x i-tile x j-half), 256 thr = 4 waves x 16 rows.
// Per 32-j iteration: stage 12KB (8KB K hi/lo + 4KB vT) with 12 gload_lds
// split 3-per-wave, double-buffered, ONE __syncthreads per iter (its implicit
// vmcnt(0) drains stage + attn stores). Frag reads = swizzled ds_read_b128.
__global__ __launch_bounds__(256, 4) void k_pass2(
    const unsigned short* __restrict__ qhi, const unsigned short* __restrict__ qlo,
    const unsigned short* __restrict__ khi, const unsigned short* __restrict__ klo,
    const unsigned short* __restrict__ vT,
    const float* __restrict__ ts, const int* __restrict__ am,
    const float* __restrict__ dlam,
    const float* __restrict__ rs_part,
    float* __restrict__ attn,
    unsigned short* __restrict__ p0hi, unsigned short* __restrict__ p0lo,
    unsigned short* __restrict__ p1hi, unsigned short* __restrict__ p1lo)
{
  __shared__ __align__(16) unsigned short K_t[2][2][32][64]; // [buf][hi/lo][row][128B]
  __shared__ __align__(16) unsigned short V_t[2][64][32];    // [buf][d][64B]
  __shared__ __align__(16) float ts_l[1024];
  __shared__ __align__(16) float mb_l[1024];
  __shared__ __align__(16) unsigned int pb[4][16][20];       // [wave][i-row][pad]
  const int w = threadIdx.x >> 6, lane = threadIdx.x & 63;
  const int lr = lane & 15, lk = lane >> 4;
  const int wg = blockIdx.x;
  const int sw = (wg & 7)*256 + (wg >> 3);
  const int bh = sw >> 6, rem = sw & 63, it = rem >> 1, jh = rem & 1;
  const int b = bh >> 3, h = bh & 7;
  const int i0 = it*64 + w*16;
  const int j0 = jh*1024;

  const float* tsb = ts + b*S_LEN;
  const int*   amb = am + b*S_LEN;
  for (int i = threadIdx.x; i < 1024; i += 256){
    ts_l[i] = tsb[j0+i];
    mb_l[i] = amb[j0+i] ? 0.f : -1e30f;
  }

  float nlam2 = -log1pf(expf(dlam[h])) * 1.44269504f;
  nlam2 = __uint_as_float(__builtin_amdgcn_readfirstlane(__float_as_uint(nlam2)));

  size_t qoff = ((size_t)bh*S_LEN + i0 + lr)*HDIM + lk*8;
  const short8v qh0 = *(const short8v*)(qhi + qoff);
  const short8v qh1 = *(const short8v*)(qhi + qoff + 32);
  const short8v ql0 = *(const short8v*)(qlo + qoff);
  const short8v ql1 = *(const short8v*)(qlo + qoff + 32);
  const float ti = tsb[i0 + lr];

  float tot = rs_part[(size_t)bh*S_LEN + i0 + lr]
            + rs_part[(size_t)(BHN + bh)*S_LEN + i0 + lr];
  const float rinv = tot > 0.f ? 1.f/tot : 0.f;

  const unsigned short* kbh = khi + ((size_t)bh*S_LEN + j0)*HDIM;
  const unsigned short* kbl = klo + ((size_t)bh*S_LEN + j0)*HDIM;
  const unsigned short* vtb = vT + (size_t)bh*HDIM*S_LEN;
  unsigned int* pbw = &pb[w][0][0];

  // staging sources (wave w stages its quarter of each tile)
  const int ksw = ((lane&7)^((lane>>3)&7))*8;              // K src col16 swizzle
  const unsigned short* ksrc_h = kbh + (lane>>3)*64 + ksw + w*512;
  const unsigned short* ksrc_l = kbl + (lane>>3)*64 + ksw + w*512;
  const unsigned short* vsrc = vtb + ((size_t)(w*16 + (lane>>2)))*S_LEN + j0
                             + (((lane&3)^((lane>>4)&3))*8);
  unsigned short* kdst_h = &K_t[0][0][0][0] + w*512;       // buf stride 4096
  unsigned short* kdst_l = &K_t[0][1][0][0] + w*512;
  unsigned short* vdst   = &V_t[0][0][0]    + w*512;       // buf stride 2048

  const unsigned int abase = (unsigned int)(bh*S_LEN + i0 + lr)*S_LEN + j0;

  // prologue: stage tile 0
  gll16(ksrc_h, kdst_h);
  gll16(ksrc_l, kdst_l);
  gll16(vsrc,   vdst);
  __syncthreads();

  f32x4 oaccT0 = (f32x4){0.f,0.f,0.f,0.f};
  f32x4 oaccT1 = (f32x4){0.f,0.f,0.f,0.f};
  f32x4 oaccT2 = (f32x4){0.f,0.f,0.f,0.f};
  f32x4 oaccT3 = (f32x4){0.f,0.f,0.f,0.f};

  for (int t = 0; t < 32; ++t){
    const int c = t & 1;
    if (t < 31){
      gll16(ksrc_h + (t+1)*2048, kdst_h + (c^1)*4096);
      gll16(ksrc_l + (t+1)*2048, kdst_l + (c^1)*4096);
      gll16(vsrc   + (t+1)*32,   vdst   + (c^1)*2048);
    }
#pragma unroll
    for (int s = 0; s < 2; ++s){
      const unsigned short* Kr0 = &K_t[c][0][s*16 + lr][0];
      const unsigned short* Kr1 = &K_t[c][1][s*16 + lr][0];
      short8v kh0 = *(const short8v*)(Kr0 + ((lk ^ (lr&7))*8));
      short8v kh1 = *(const short8v*)(Kr0 + (((4+lk) ^ (lr&7))*8));
      short8v kl0 = *(const short8v*)(Kr1 + ((lk ^ (lr&7))*8));
      short8v kl1 = *(const short8v*)(Kr1 + (((4+lk) ^ (lr&7))*8));
      // swapped QK: split accumulators (4-chain corrections + 2-chain hi)
      f32x4 s1 = (f32x4){0.f,0.f,0.f,0.f};
      s1 = mfma16(kh0, ql0, s1);
      s1 = mfma16(kl0, qh0, s1);
      s1 = mfma16(kh1, ql1, s1);
      s1 = mfma16(kl1, qh1, s1);
      f32x4 s2 = (f32x4){0.f,0.f,0.f,0.f};
      s2 = mfma16(kh0, qh0, s2);
      s2 = mfma16(kh1, qh1, s2);
      const int jb = t*32 + s*16 + lk*4;
      f32x4 ts4 = *(const f32x4*)&ts_l[jb];
      f32x4 mb4 = *(const f32x4*)&mb_l[jb];
      f32x4 pv;
#pragma unroll
      for (int r=0;r<4;++r){
        float sa = s1[r] + s2[r];
        float dec = __builtin_amdgcn_exp2f(nlam2 * fabsf(ti - ts4[r]));
        float e = __builtin_amdgcn_exp2f(__builtin_fmaf(sa, dec, mb4[r]));
        pv[r] = e * rinv;
      }
      *(f32x4*)(attn + abase + jb) = pv;   // one coalesced 16B store
      uint2v pk; pk.x = pack2bf(pv[0], pv[1]); pk.y = pack2bf(pv[2], pv[3]);
      *(uint2v*)&pbw[lr*20 + s*8 + 2*lk] = pk;
    }
    // PV for this 32-j chunk: pa = P[i=lr][j = 8*lk .. 8*lk+7]
    short8v pa = *(const short8v*)&pbw[lr*20 + 4*lk];
    const int vsw = (lr>>2)&3;
    short8v vf0 = *(const short8v*)&V_t[c][ 0 + lr][(lk ^ vsw)*8];
    short8v vf1 = *(const short8v*)&V_t[c][16 + lr][(lk ^ vsw)*8];
    short8v vf2 = *(const short8v*)&V_t[c][32 + lr][(lk ^ vsw)*8];
    short8v vf3 = *(const short8v*)&V_t[c][48 + lr][(lk ^ vsw)*8];
    oaccT0 = mfma16(vf0, pa, oaccT0);
    oaccT1 = mfma16(vf1, pa, oaccT1);
    oaccT2 = mfma16(vf2, pa, oaccT2);
    oaccT3 = mfma16(vf3, pa, oaccT3);
    __syncthreads();   // stage(t+1) drained; all waves done with buf c
  }

  // epilogue: O^T frag -> O[i=i0+lr][d = nt*16 + lk*4 + r], split bf16
  unsigned short* phi = jh ? p1hi : p0hi;
  unsigned short* plo = jh ? p1lo : p0lo;
  const size_t rowb = (size_t)(b*S_LEN + i0 + lr)*DM + h*HDIM + lk*4;
  float oa[4][4] = {
    {oaccT0[0],oaccT0[1],oaccT0[2],oaccT0[3]},
    {oaccT1[0],oaccT1[1],oaccT1[2],oaccT1[3]},
    {oaccT2[0],oaccT2[1],oaccT2[2],oaccT2[3]},
    {oaccT3[0],oaccT3[1],oaccT3[2],oaccT3[3]}};
#pragma unroll
  for (int nt=0;nt<4;++nt){
    ushort4v hh, ll;
#pragma unroll
    for (int r=0;r<4;++r){
      float vv = oa[nt][r];
      unsigned short hb = bf16_rne(vv);
      hh[r] = hb;
      ll[r] = bf16_rne(vv - bf16_f32(hb));
    }
    *(ushort4v*)(phi + rowb + nt*16) = hh;
    *(ushort4v*)(plo + rowb + nt*16) = ll;
  }
}

// ---------------- combine partial O halves -> split bf16 into (oh,ol) --------
__global__ __launch_bounds__(256) void k_combine(
    const unsigned short* __restrict__ h1, const unsigned short* __restrict__ l1,
    unsigned short* __restrict__ oh, unsigned short* __restrict__ ol, int n8)
{
  int i = blockIdx.x*blockDim.x + threadIdx.x;
  if (i >= n8) return;
  size_t base = (size_t)i*8;
  ushort8v a = *(const ushort8v*)(oh + base);   // jh=0 hi (in place)
  ushort8v bq = *(const ushort8v*)(ol + base);  // jh=0 lo
  ushort8v c = *(const ushort8v*)(h1 + base);
  ushort8v d = *(const ushort8v*)(l1 + base);
  ushort8v rh, rl;
#pragma unroll
  for (int j=0;j<8;++j){
    float f = bf16_f32(a[j]) + bf16_f32(bq[j]) + bf16_f32(c[j]) + bf16_f32(d[j]);
    unsigned short hb = bf16_rne(f);
    rh[j] = hb;
    rl[j] = bf16_rne(f - bf16_f32(hb));
  }
  *(ushort8v*)(oh + base) = rh;
  *(ushort8v*)(ol + base) = rl;
}

// ---------------------------------------------------------------------------
extern "C" void kernel_launch(void* const* d_in, const int* in_sizes, int n_in,
                              void* d_out, int out_size, void* d_ws, size_t ws_size,
                              hipStream_t stream){
  const float* x  = (const float*)d_in[0];
  const float* ts = (const float*)d_in[1];
  const int*   am = (const int*)d_in[2];
  const float* Wq = (const float*)d_in[3];
  const float* bq = (const float*)d_in[4];
  const float* Wk = (const float*)d_in[5];
  const float* bk = (const float*)d_in[6];
  const float* Wv = (const float*)d_in[7];
  const float* bv = (const float*)d_in[8];
  const float* Wo = (const float*)d_in[9];
  const float* bo = (const float*)d_in[10];
  const float* dl = (const float*)d_in[11];

  char* ws = (char*)d_ws;
  unsigned short* xhi = (unsigned short*)(ws);               // x-split; later final opre hi
  unsigned short* xlo = (unsigned short*)(ws + 8388608ull);  // x-split; later final opre lo
  unsigned short* wqt_hi = (unsigned short*)(ws + 16777216ull + 0ull*524288ull);
  unsigned short* wqt_lo = (unsigned short*)(ws + 16777216ull + 1ull*524288ull);
  unsigned short* wkt_hi = (unsigned short*)(ws + 16777216ull + 2ull*524288ull);
  unsigned short* wkt_lo = (unsigned short*)(ws + 16777216ull + 3ull*524288ull);
  unsigned short* wvt_hi = (unsigned short*)(ws + 16777216ull + 4ull*524288ull);
  unsigned short* wvt_lo = (unsigned short*)(ws + 16777216ull + 5ull*524288ull);
  unsigned short* wot_hi = (unsigned short*)(ws + 16777216ull + 6ull*524288ull);
  unsigned short* wot_lo = (unsigned short*)(ws + 16777216ull + 7ull*524288ull);
  unsigned short* qhi = (unsigned short*)(ws + 20971520ull + 0ull*8388608ull);
  unsigned short* qlo = (unsigned short*)(ws + 20971520ull + 1ull*8388608ull);
  unsigned short* khi = (unsigned short*)(ws + 20971520ull + 2ull*8388608ull);
  unsigned short* klo = (unsigned short*)(ws + 20971520ull + 3ull*8388608ull);
  unsigned short* vv  = (unsigned short*)(ws + 20971520ull + 4ull*8388608ull);
  unsigned short* vt  = (unsigned short*)(ws + 20971520ull + 5ull*8388608ull);
  // rs_part reuses the retired Wq slot (free after the q GEMM): 512 KB
  float* rs_part = (float*)(ws + 16777216ull);

  float* outp  = (float*)d_out;
  float* attnp = outp + (size_t)BSROWS*DM;
  // jh=1 partial O stashed in the out0 region (scratch until final GEMM)
  unsigned short* p1hi = (unsigned short*)d_out;
  unsigned short* p1lo = p1hi + 4194304ull;

  k_split<<<4096, 256, 0, stream>>>(x, xhi, xlo, BSROWS*DM);
  k_wsplit<<<1024, 256, 0, stream>>>(Wq, wqt_hi, wqt_lo);
  k_wsplit<<<1024, 256, 0, stream>>>(Wk, wkt_hi, wkt_lo);
  k_wsplit<<<1024, 256, 0, stream>>>(Wv, wvt_hi, wvt_lo);
  k_wsplit<<<1024, 256, 0, stream>>>(Wo, wot_hi, wot_lo);

  dim3 pg(DM/64, BSROWS/128);
  // q pre-scaled by hd^-0.5 * log2(e)
  k_gemm_split<<<pg, 256, 0, stream>>>(xhi, xlo, wqt_hi, wqt_lo, bq,
                                       nullptr, qhi, qlo, BSROWS, DM, DM, 0,
                                       0.18033688f);
  k_gemm_split<<<pg, 256, 0, stream>>>(xhi, xlo, wkt_hi, wkt_lo, bk,
                                       nullptr, khi, klo, BSROWS, DM, DM, 0, 1.f);
  k_gemm_split<<<pg, 256, 0, stream>>>(xhi, xlo, wvt_hi, wvt_lo, bv,
                                       nullptr, vv, nullptr, BSROWS, DM, DM, 1, 1.f);
  k_transpose_v<<<dim3(S_LEN/64, BHN), 256, 0, stream>>>(vv, vt);

  k_rowsum<<<2048, 256, 0, stream>>>(qhi, khi, ts, am, dl, rs_part);
  k_pass2<<<2048, 256, 0, stream>>>(qhi, qlo, khi, klo, vt, ts, am, dl,
                                    rs_part, attnp, xhi, xlo, p1hi, p1lo);
  k_combine<<<2048, 256, 0, stream>>>(p1hi, p1lo, xhi, xlo, 524288);
  k_gemm_split<<<pg, 256, 0, stream>>>(xhi, xlo, wot_hi, wot_lo, bo,
                                       outp, nullptr, nullptr, BSROWS, DM, DM, 2, 1.f);

  (void)in_sizes; (void)n_in; (void)out_size; (void)ws_size;
}

// Round 8
// 399.615 us; speedup vs baseline: 2.4087x; 1.2623x over previous
//
#include <hip/hip_runtime.h>

// ---------------------------------------------------------------------------
// AdaptiveTemporalAttention — MI355X gfx950
// B=4, S=2048, D=512, H=8, hd=64.
// Outputs: out (B,S,D) f32 then attn (B,H,S,S) f32, concatenated in d_out.
//
// Round 8: LDS-staged split-GEMM (m97 2-phase pattern, BK=32, dbuf,
// global_load_lds w=16, chunk-XOR swizzle c^=(row>>1)&3 on stage-source and
// ds_read -> conflict-free). R7 proved the VMEM-request-stream model on
// attention (752->504); the GEMM stack had the identical pathology.
// Also: v-GEMM epilogue writes vT[bh][d][s] directly (4 consecutive s at
// fixed d = one ushort4 store) -> k_transpose_v deleted.
// Attention kernels unchanged from round 7.
// ---------------------------------------------------------------------------

#define S_LEN  2048
#define DM     512
#define NH     8
#define HDIM   64
#define BATCH  4
#define BHN    32     // BATCH*NH
#define BSROWS 8192   // BATCH*S_LEN

typedef __attribute__((ext_vector_type(8))) short short8v;
typedef __attribute__((ext_vector_type(8))) unsigned short ushort8v;
typedef __attribute__((ext_vector_type(4))) unsigned short ushort4v;
typedef __attribute__((ext_vector_type(4))) float f32x4;
typedef __attribute__((ext_vector_type(2))) unsigned int uint2v;

static __device__ __forceinline__ unsigned short bf16_rne(float f){
  unsigned int u = __float_as_uint(f);
  u = (u + 0x7FFFu + ((u >> 16) & 1u)) >> 16;
  return (unsigned short)u;
}
static __device__ __forceinline__ float bf16_f32(unsigned short h){
  return __uint_as_float(((unsigned int)h) << 16);
}
static __device__ __forceinline__ unsigned int pack2bf(float a, float b){
  return (unsigned int)bf16_rne(a) | ((unsigned int)bf16_rne(b) << 16);
}
static __device__ __forceinline__ f32x4 mfma16(short8v a, short8v b, f32x4 c){
  return __builtin_amdgcn_mfma_f32_16x16x32_bf16(a, b, c, 0, 0, 0);
}
// async global->LDS, 16B/lane; LDS dst wave-uniform (HW appends lane*16)
static __device__ __forceinline__ void gll16(const unsigned short* g, unsigned short* l){
  __builtin_amdgcn_global_load_lds(
      (const __attribute__((address_space(1))) unsigned int*)g,
      (__attribute__((address_space(3))) unsigned int*)l, 16, 0, 0);
}

// ---------------- prep: elementwise split f32 -> (hi,lo) bf16 ----------------
__global__ void k_split(const float* __restrict__ src,
                        unsigned short* __restrict__ hi,
                        unsigned short* __restrict__ lo, int n){
  for (int i = blockIdx.x*blockDim.x + threadIdx.x; i < n;
       i += gridDim.x*blockDim.x){
    float f = src[i];
    unsigned short h = bf16_rne(f);
    hi[i] = h;
    lo[i] = bf16_rne(f - bf16_f32(h));
  }
}

// ---------------- prep: transpose 512x512 W -> WT, split ----------------
__global__ void k_wsplit(const float* __restrict__ W,
                         unsigned short* __restrict__ Thi,
                         unsigned short* __restrict__ Tlo){
  int idx = blockIdx.x*blockDim.x + threadIdx.x; // (n,k) with k fastest
  int n = idx >> 9, k = idx & 511;
  float f = W[k*DM + n];
  unsigned short h = bf16_rne(f);
  Thi[idx] = h;
  Tlo[idx] = bf16_rne(f - bf16_f32(h));
}

// ---------------- LDS-staged split-precision GEMM ----------------
// C = (A@B + bias)*cscale.  A: Ahi/Alo [M][K], B: BThi/BTlo [N][K].
// Tile 128x64, 4 waves (64x32 each), BK=32, double-buffered gload_lds.
// Swizzle: LDS[row][chunk] = G[row][chunk ^ ((row>>1)&3)], chunk=16B unit.
// mode 0: split bf16 -> [b][h][s][d]   (q/k)
// mode 1: bf16 -> vT[bh][d][s] DIRECT  (v, transposed write)
// mode 2: f32 -> outF[row*N+col]       (final out)
__global__ __launch_bounds__(256, 3) void k_gemm_split(
    const unsigned short* __restrict__ Ahi, const unsigned short* __restrict__ Alo,
    const unsigned short* __restrict__ BThi, const unsigned short* __restrict__ BTlo,
    const float* __restrict__ bias,
    float* __restrict__ outF,
    unsigned short* __restrict__ outHi, unsigned short* __restrict__ outLo,
    int M, int N, int K, int mode, float cscale)
{
  __shared__ __align__(16) unsigned short At[2][2][128][32]; // [buf][hl][row][k]
  __shared__ __align__(16) unsigned short Bt[2][2][64][32];
  const int lane = threadIdx.x & 63, w = threadIdx.x >> 6;
  const int lr = lane & 15, lk = lane >> 4;
  const int rowbase = blockIdx.y*128;
  const int colbase = blockIdx.x*64;
  const int wrow = (w >> 1)*64;       // wave's row offset in tile
  const int wcol = (w & 1)*32;        // wave's col offset in tile

  // staging addresses: wave w stages tile rows w*16+(lane>>2) (+64 for A's 2nd)
  const int srow = w*16 + (lane>>2);
  const int ssw  = ((lane&3) ^ ((lane>>3)&3))*8;   // source chunk swizzle (shorts)
  const unsigned short* asrc_h = Ahi + (size_t)(rowbase + srow)*K + ssw;
  const unsigned short* asrc_l = Alo + (size_t)(rowbase + srow)*K + ssw;
  const unsigned short* bsrc_h = BThi + (size_t)(colbase + srow)*K + ssw;
  const unsigned short* bsrc_l = BTlo + (size_t)(colbase + srow)*K + ssw;
  unsigned short* adst_h = &At[0][0][w*16][0];     // buf stride 8192 shorts
  unsigned short* adst_l = &At[0][1][w*16][0];
  unsigned short* bdst_h = &Bt[0][0][w*16][0];     // buf stride 4096 shorts
  unsigned short* bdst_l = &Bt[0][1][w*16][0];

#define GSTAGE(KS, BB) { \
    int k0_ = (KS)*32; \
    gll16(asrc_h + k0_,              adst_h + (BB)*8192); \
    gll16(asrc_h + (size_t)64*K + k0_, adst_h + (BB)*8192 + 2048); \
    gll16(asrc_l + k0_,              adst_l + (BB)*8192); \
    gll16(asrc_l + (size_t)64*K + k0_, adst_l + (BB)*8192 + 2048); \
    gll16(bsrc_h + k0_,              bdst_h + (BB)*4096); \
    gll16(bsrc_l + k0_,              bdst_l + (BB)*4096); }

  // frag read bases (chunk = lk ^ ((lr>>1)&3); row-base bits contribute 0)
  const int csw = (lk ^ ((lr>>1)&3))*8;
  const unsigned short* Ard_h = &At[0][0][wrow + lr][0] + csw;
  const unsigned short* Ard_l = &At[0][1][wrow + lr][0] + csw;
  const unsigned short* Brd_h = &Bt[0][0][wcol + lr][0] + csw;
  const unsigned short* Brd_l = &Bt[0][1][wcol + lr][0] + csw;

  f32x4 acc[4][2];
#pragma unroll
  for (int mi=0; mi<4; ++mi)
#pragma unroll
    for (int ni=0; ni<2; ++ni) acc[mi][ni] = (f32x4){0.f,0.f,0.f,0.f};

  GSTAGE(0, 0);
  __syncthreads();

  const int NKS = K >> 5;
  for (int ks = 0; ks < NKS; ++ks){
    const int c = ks & 1;
    if (ks + 1 < NKS) GSTAGE(ks+1, c^1);
    short8v ah[4], al[4], bhf[2], blf[2];
#pragma unroll
    for (int mi=0; mi<4; ++mi){
      ah[mi] = *(const short8v*)(Ard_h + c*8192 + mi*512);
      al[mi] = *(const short8v*)(Ard_l + c*8192 + mi*512);
    }
#pragma unroll
    for (int ni=0; ni<2; ++ni){
      bhf[ni] = *(const short8v*)(Brd_h + c*4096 + ni*512);
      blf[ni] = *(const short8v*)(Brd_l + c*4096 + ni*512);
    }
#pragma unroll
    for (int mi=0; mi<4; ++mi)
#pragma unroll
      for (int ni=0; ni<2; ++ni){
        acc[mi][ni] = mfma16(ah[mi], blf[ni], acc[mi][ni]);
        acc[mi][ni] = mfma16(al[mi], bhf[ni], acc[mi][ni]);
        acc[mi][ni] = mfma16(ah[mi], bhf[ni], acc[mi][ni]);
      }
    __syncthreads();
  }
#undef GSTAGE

#pragma unroll
  for (int mi=0; mi<4; ++mi)
#pragma unroll
    for (int ni=0; ni<2; ++ni){
      const int col = colbase + wcol + ni*16 + lr;
      const int row0 = rowbase + wrow + mi*16 + lk*4;  // 4 consecutive rows
      if (mode == 1){
        // direct transposed write: vT[bh][d][s], 4 consecutive s
        int b = row0 >> 11, s0 = row0 & 2047, hh = col >> 6, d = col & 63;
        ushort4v t;
#pragma unroll
        for (int r=0;r<4;++r)
          t[r] = bf16_rne((acc[mi][ni][r] + bias[col]) * cscale);
        *(ushort4v*)(outHi + ((size_t)(b*NH + hh)*HDIM + d)*S_LEN + s0) = t;
      } else {
#pragma unroll
        for (int r=0;r<4;++r){
          int row = row0 + r;
          float cvl = (acc[mi][ni][r] + bias[col]) * cscale;
          if (mode == 2){
            outF[(size_t)row*N + col] = cvl;
          } else {
            int b = row >> 11, s = row & 2047, hh = col >> 6, d = col & 63;
            size_t off = (((size_t)(b*NH + hh))*S_LEN + s)*HDIM + d;
            unsigned short hb = bf16_rne(cvl);
            outHi[off] = hb;
            outLo[off] = bf16_rne(cvl - bf16_f32(hb));
          }
        }
      }
    }
}

// ---------------- rowsum kernel (LDS-staged K-hi, swapped QK) ----------------
__global__ __launch_bounds__(256) void k_rowsum(
    const unsigned short* __restrict__ qhi,
    const unsigned short* __restrict__ khi,
    const float* __restrict__ ts, const int* __restrict__ am,
    const float* __restrict__ dlam,
    float* __restrict__ rs_part)
{
  __shared__ __align__(16) unsigned short K_t[2][32][64];  // [buf][row][128B], swz
  __shared__ __align__(16) float ts_l[1024];
  __shared__ __align__(16) float mb_l[1024];
  const int w = threadIdx.x >> 6, lane = threadIdx.x & 63;
  const int lr = lane & 15, lk = lane >> 4;
  const int wg = blockIdx.x;
  const int sw = (wg & 7)*256 + (wg >> 3);
  const int bh = sw >> 6, rem = sw & 63, it = rem >> 1, jh = rem & 1;
  const int b = bh >> 3, h = bh & 7;
  const int i0 = it*64 + w*16;
  const int j0 = jh*1024;

  const float* tsb = ts + b*S_LEN;
  const int*   amb = am + b*S_LEN;
  for (int i = threadIdx.x; i < 1024; i += 256){
    ts_l[i] = tsb[j0+i];
    mb_l[i] = amb[j0+i] ? 0.f : -1e30f;
  }

  float nlam2 = -log1pf(expf(dlam[h])) * 1.44269504f;
  nlam2 = __uint_as_float(__builtin_amdgcn_readfirstlane(__float_as_uint(nlam2)));

  size_t qoff = ((size_t)bh*S_LEN + i0 + lr)*HDIM + lk*8;
  const short8v qh0 = *(const short8v*)(qhi + qoff);
  const short8v qh1 = *(const short8v*)(qhi + qoff + 32);
  const float ti = tsb[i0 + lr];

  const unsigned short* kbh = khi + ((size_t)bh*S_LEN + j0)*HDIM;
  const unsigned short* ksrc = kbh + ((lane>>3))*64
                             + (((lane&7)^((lane>>3)&7))*8) + w*512;
  unsigned short* kdst = &K_t[0][0][0] + w*512;        // buf stride 2048 shorts

  gll16(ksrc, kdst);                                   // t=0
  __syncthreads();

  float rs = 0.f;
  for (int t = 0; t < 32; ++t){
    const int c = t & 1;
    if (t < 31) gll16(ksrc + (t+1)*2048, kdst + (c^1)*2048);
#pragma unroll
    for (int s = 0; s < 2; ++s){
      const unsigned short* Kr = &K_t[c][s*16 + lr][0];
      short8v a0 = *(const short8v*)(Kr + ((lk ^ (lr&7))*8));
      short8v a1 = *(const short8v*)(Kr + (((4+lk) ^ (lr&7))*8));
      f32x4 sA = (f32x4){0.f,0.f,0.f,0.f};
      sA = mfma16(a0, qh0, sA);
      sA = mfma16(a1, qh1, sA);
      const int jb = t*32 + s*16 + lk*4;
      f32x4 ts4 = *(const f32x4*)&ts_l[jb];
      f32x4 mb4 = *(const f32x4*)&mb_l[jb];
#pragma unroll
      for (int r=0;r<4;++r){
        float dec = __builtin_amdgcn_exp2f(nlam2 * fabsf(ti - ts4[r]));
        rs += __builtin_amdgcn_exp2f(__builtin_fmaf(sA[r], dec, mb4[r]));
      }
    }
    __syncthreads();
  }
  rs += __shfl_xor(rs, 16, 64);
  rs += __shfl_xor(rs, 32, 64);
  if (lane < 16)
    rs_part[(size_t)(jh*BHN + bh)*S_LEN + i0 + lane] = rs;
}

// ---------------- pass-2: LDS-staged K+vT, attn write + partial PV ----------
__global__ __launch_bounds__(256, 4) void k_pass2(
    const unsigned short* __restrict__ qhi, const unsigned short* __restrict__ qlo,
    const unsigned short* __restrict__ khi, const unsigned short* __restrict__ klo,
    const unsigned short* __restrict__ vT,
    const float* __restrict__ ts, const int* __restrict__ am,
    const float* __restrict__ dlam,
    const float* __restrict__ rs_part,
    float* __restrict__ attn,
    unsigned short* __restrict__ p0hi, unsigned short* __restrict__ p0lo,
    unsigned short* __restrict__ p1hi, unsigned short* __restrict__ p1lo)
{
  __shared__ __align__(16) unsigned short K_t[2][2][32][64]; // [buf][hi/lo][row][128B]
  __shared__ __align__(16) unsigned short V_t[2][64][32];    // [buf][d][64B]
  __shared__ __align__(16) float ts_l[1024];
  __shared__ __align__(16) float mb_l[1024];
  __shared__ __align__(16) unsigned int pb[4][16][20];       // [wave][i-row][pad]
  const int w = threadIdx.x >> 6, lane = threadIdx.x & 63;
  const int lr = lane & 15, lk = lane >> 4;
  const int wg = blockIdx.x;
  const int sw = (wg & 7)*256 + (wg >> 3);
  const int bh = sw >> 6, rem = sw & 63, it = rem >> 1, jh = rem & 1;
  const int b = bh >> 3, h = bh & 7;
  const int i0 = it*64 + w*16;
  const int j0 = jh*1024;

  const float* tsb = ts + b*S_LEN;
  const int*   amb = am + b*S_LEN;
  for (int i = threadIdx.x; i < 1024; i += 256){
    ts_l[i] = tsb[j0+i];
    mb_l[i] = amb[j0+i] ? 0.f : -1e30f;
  }

  float nlam2 = -log1pf(expf(dlam[h])) * 1.44269504f;
  nlam2 = __uint_as_float(__builtin_amdgcn_readfirstlane(__float_as_uint(nlam2)));

  size_t qoff = ((size_t)bh*S_LEN + i0 + lr)*HDIM + lk*8;
  const short8v qh0 = *(const short8v*)(qhi + qoff);
  const short8v qh1 = *(const short8v*)(qhi + qoff + 32);
  const short8v ql0 = *(const short8v*)(qlo + qoff);
  const short8v ql1 = *(const short8v*)(qlo + qoff + 32);
  const float ti = tsb[i0 + lr];

  float tot = rs_part[(size_t)bh*S_LEN + i0 + lr]
            + rs_part[(size_t)(BHN + bh)*S_LEN + i0 + lr];
  const float rinv = tot > 0.f ? 1.f/tot : 0.f;

  const unsigned short* kbh = khi + ((size_t)bh*S_LEN + j0)*HDIM;
  const unsigned short* kbl = klo + ((size_t)bh*S_LEN + j0)*HDIM;
  const unsigned short* vtb = vT + (size_t)bh*HDIM*S_LEN;
  unsigned int* pbw = &pb[w][0][0];

  const int ksw = ((lane&7)^((lane>>3)&7))*8;              // K src col16 swizzle
  const unsigned short* ksrc_h = kbh + (lane>>3)*64 + ksw + w*512;
  const unsigned short* ksrc_l = kbl + (lane>>3)*64 + ksw + w*512;
  const unsigned short* vsrc = vtb + ((size_t)(w*16 + (lane>>2)))*S_LEN + j0
                             + (((lane&3)^((lane>>4)&3))*8);
  unsigned short* kdst_h = &K_t[0][0][0][0] + w*512;       // buf stride 4096
  unsigned short* kdst_l = &K_t[0][1][0][0] + w*512;
  unsigned short* vdst   = &V_t[0][0][0]    + w*512;       // buf stride 2048

  const unsigned int abase = (unsigned int)(bh*S_LEN + i0 + lr)*S_LEN + j0;

  gll16(ksrc_h, kdst_h);
  gll16(ksrc_l, kdst_l);
  gll16(vsrc,   vdst);
  __syncthreads();

  f32x4 oaccT0 = (f32x4){0.f,0.f,0.f,0.f};
  f32x4 oaccT1 = (f32x4){0.f,0.f,0.f,0.f};
  f32x4 oaccT2 = (f32x4){0.f,0.f,0.f,0.f};
  f32x4 oaccT3 = (f32x4){0.f,0.f,0.f,0.f};

  for (int t = 0; t < 32; ++t){
    const int c = t & 1;
    if (t < 31){
      gll16(ksrc_h + (t+1)*2048, kdst_h + (c^1)*4096);
      gll16(ksrc_l + (t+1)*2048, kdst_l + (c^1)*4096);
      gll16(vsrc   + (t+1)*32,   vdst   + (c^1)*2048);
    }
#pragma unroll
    for (int s = 0; s < 2; ++s){
      const unsigned short* Kr0 = &K_t[c][0][s*16 + lr][0];
      const unsigned short* Kr1 = &K_t[c][1][s*16 + lr][0];
      short8v kh0 = *(const short8v*)(Kr0 + ((lk ^ (lr&7))*8));
      short8v kh1 = *(const short8v*)(Kr0 + (((4+lk) ^ (lr&7))*8));
      short8v kl0 = *(const short8v*)(Kr1 + ((lk ^ (lr&7))*8));
      short8v kl1 = *(const short8v*)(Kr1 + (((4+lk) ^ (lr&7))*8));
      f32x4 s1 = (f32x4){0.f,0.f,0.f,0.f};
      s1 = mfma16(kh0, ql0, s1);
      s1 = mfma16(kl0, qh0, s1);
      s1 = mfma16(kh1, ql1, s1);
      s1 = mfma16(kl1, qh1, s1);
      f32x4 s2 = (f32x4){0.f,0.f,0.f,0.f};
      s2 = mfma16(kh0, qh0, s2);
      s2 = mfma16(kh1, qh1, s2);
      const int jb = t*32 + s*16 + lk*4;
      f32x4 ts4 = *(const f32x4*)&ts_l[jb];
      f32x4 mb4 = *(const f32x4*)&mb_l[jb];
      f32x4 pv;
#pragma unroll
      for (int r=0;r<4;++r){
        float sa = s1[r] + s2[r];
        float dec = __builtin_amdgcn_exp2f(nlam2 * fabsf(ti - ts4[r]));
        float e = __builtin_amdgcn_exp2f(__builtin_fmaf(sa, dec, mb4[r]));
        pv[r] = e * rinv;
      }
      *(f32x4*)(attn + abase + jb) = pv;   // one coalesced 16B store
      uint2v pk; pk.x = pack2bf(pv[0], pv[1]); pk.y = pack2bf(pv[2], pv[3]);
      *(uint2v*)&pbw[lr*20 + s*8 + 2*lk] = pk;
    }
    short8v pa = *(const short8v*)&pbw[lr*20 + 4*lk];
    const int vsw = (lr>>2)&3;
    short8v vf0 = *(const short8v*)&V_t[c][ 0 + lr][(lk ^ vsw)*8];
    short8v vf1 = *(const short8v*)&V_t[c][16 + lr][(lk ^ vsw)*8];
    short8v vf2 = *(const short8v*)&V_t[c][32 + lr][(lk ^ vsw)*8];
    short8v vf3 = *(const short8v*)&V_t[c][48 + lr][(lk ^ vsw)*8];
    oaccT0 = mfma16(vf0, pa, oaccT0);
    oaccT1 = mfma16(vf1, pa, oaccT1);
    oaccT2 = mfma16(vf2, pa, oaccT2);
    oaccT3 = mfma16(vf3, pa, oaccT3);
    __syncthreads();   // stage(t+1) drained; all waves done with buf c
  }

  unsigned short* phi = jh ? p1hi : p0hi;
  unsigned short* plo = jh ? p1lo : p0lo;
  const size_t rowb = (size_t)(b*S_LEN + i0 + lr)*DM + h*HDIM + lk*4;
  float oa[4][4] = {
    {oaccT0[0],oaccT0[1],oaccT0[2],oaccT0[3]},
    {oaccT1[0],oaccT1[1],oaccT1[2],oaccT1[3]},
    {oaccT2[0],oaccT2[1],oaccT2[2],oaccT2[3]},
    {oaccT3[0],oaccT3[1],oaccT3[2],oaccT3[3]}};
#pragma unroll
  for (int nt=0;nt<4;++nt){
    ushort4v hh, ll;
#pragma unroll
    for (int r=0;r<4;++r){
      float vv = oa[nt][r];
      unsigned short hb = bf16_rne(vv);
      hh[r] = hb;
      ll[r] = bf16_rne(vv - bf16_f32(hb));
    }
    *(ushort4v*)(phi + rowb + nt*16) = hh;
    *(ushort4v*)(plo + rowb + nt*16) = ll;
  }
}

// ---------------- combine partial O halves -> split bf16 into (oh,ol) --------
__global__ __launch_bounds__(256) void k_combine(
    const unsigned short* __restrict__ h1, const unsigned short* __restrict__ l1,
    unsigned short* __restrict__ oh, unsigned short* __restrict__ ol, int n8)
{
  int i = blockIdx.x*blockDim.x + threadIdx.x;
  if (i >= n8) return;
  size_t base = (size_t)i*8;
  ushort8v a = *(const ushort8v*)(oh + base);   // jh=0 hi (in place)
  ushort8v bq = *(const ushort8v*)(ol + base);  // jh=0 lo
  ushort8v c = *(const ushort8v*)(h1 + base);
  ushort8v d = *(const ushort8v*)(l1 + base);
  ushort8v rh, rl;
#pragma unroll
  for (int j=0;j<8;++j){
    float f = bf16_f32(a[j]) + bf16_f32(bq[j]) + bf16_f32(c[j]) + bf16_f32(d[j]);
    unsigned short hb = bf16_rne(f);
    rh[j] = hb;
    rl[j] = bf16_rne(f - bf16_f32(hb));
  }
  *(ushort8v*)(oh + base) = rh;
  *(ushort8v*)(ol + base) = rl;
}

// ---------------------------------------------------------------------------
extern "C" void kernel_launch(void* const* d_in, const int* in_sizes, int n_in,
                              void* d_out, int out_size, void* d_ws, size_t ws_size,
                              hipStream_t stream){
  const float* x  = (const float*)d_in[0];
  const float* ts = (const float*)d_in[1];
  const int*   am = (const int*)d_in[2];
  const float* Wq = (const float*)d_in[3];
  const float* bq = (const float*)d_in[4];
  const float* Wk = (const float*)d_in[5];
  const float* bk = (const float*)d_in[6];
  const float* Wv = (const float*)d_in[7];
  const float* bv = (const float*)d_in[8];
  const float* Wo = (const float*)d_in[9];
  const float* bo = (const float*)d_in[10];
  const float* dl = (const float*)d_in[11];

  char* ws = (char*)d_ws;
  unsigned short* xhi = (unsigned short*)(ws);               // x-split; later final opre hi
  unsigned short* xlo = (unsigned short*)(ws + 8388608ull);  // x-split; later final opre lo
  unsigned short* wqt_hi = (unsigned short*)(ws + 16777216ull + 0ull*524288ull);
  unsigned short* wqt_lo = (unsigned short*)(ws + 16777216ull + 1ull*524288ull);
  unsigned short* wkt_hi = (unsigned short*)(ws + 16777216ull + 2ull*524288ull);
  unsigned short* wkt_lo = (unsigned short*)(ws + 16777216ull + 3ull*524288ull);
  unsigned short* wvt_hi = (unsigned short*)(ws + 16777216ull + 4ull*524288ull);
  unsigned short* wvt_lo = (unsigned short*)(ws + 16777216ull + 5ull*524288ull);
  unsigned short* wot_hi = (unsigned short*)(ws + 16777216ull + 6ull*524288ull);
  unsigned short* wot_lo = (unsigned short*)(ws + 16777216ull + 7ull*524288ull);
  unsigned short* qhi = (unsigned short*)(ws + 20971520ull + 0ull*8388608ull);
  unsigned short* qlo = (unsigned short*)(ws + 20971520ull + 1ull*8388608ull);
  unsigned short* khi = (unsigned short*)(ws + 20971520ull + 2ull*8388608ull);
  unsigned short* klo = (unsigned short*)(ws + 20971520ull + 3ull*8388608ull);
  unsigned short* vt  = (unsigned short*)(ws + 20971520ull + 4ull*8388608ull);
  // rs_part reuses the retired Wq slot (free after the q GEMM): 512 KB
  float* rs_part = (float*)(ws + 16777216ull);

  float* outp  = (float*)d_out;
  float* attnp = outp + (size_t)BSROWS*DM;
  // jh=1 partial O stashed in the out0 region (scratch until final GEMM)
  unsigned short* p1hi = (unsigned short*)d_out;
  unsigned short* p1lo = p1hi + 4194304ull;

  k_split<<<4096, 256, 0, stream>>>(x, xhi, xlo, BSROWS*DM);
  k_wsplit<<<1024, 256, 0, stream>>>(Wq, wqt_hi, wqt_lo);
  k_wsplit<<<1024, 256, 0, stream>>>(Wk, wkt_hi, wkt_lo);
  k_wsplit<<<1024, 256, 0, stream>>>(Wv, wvt_hi, wvt_lo);
  k_wsplit<<<1024, 256, 0, stream>>>(Wo, wot_hi, wot_lo);

  dim3 pg(DM/64, BSROWS/128);
  // q pre-scaled by hd^-0.5 * log2(e)
  k_gemm_split<<<pg, 256, 0, stream>>>(xhi, xlo, wqt_hi, wqt_lo, bq,
                                       nullptr, qhi, qlo, BSROWS, DM, DM, 0,
                                       0.18033688f);
  k_gemm_split<<<pg, 256, 0, stream>>>(xhi, xlo, wkt_hi, wkt_lo, bk,
                                       nullptr, khi, klo, BSROWS, DM, DM, 0, 1.f);
  // v GEMM writes vT[bh][d][s] directly (mode 1)
  k_gemm_split<<<pg, 256, 0, stream>>>(xhi, xlo, wvt_hi, wvt_lo, bv,
                                       nullptr, vt, nullptr, BSROWS, DM, DM, 1, 1.f);

  k_rowsum<<<2048, 256, 0, stream>>>(qhi, khi, ts, am, dl, rs_part);
  k_pass2<<<2048, 256, 0, stream>>>(qhi, qlo, khi, klo, vt, ts, am, dl,
                                    rs_part, attnp, xhi, xlo, p1hi, p1lo);
  k_combine<<<2048, 256, 0, stream>>>(p1hi, p1lo, xhi, xlo, 524288);
  k_gemm_split<<<pg, 256, 0, stream>>>(xhi, xlo, wot_hi, wot_lo, bo,
                                       outp, nullptr, nullptr, BSROWS, DM, DM, 2, 1.f);

  (void)in_sizes; (void)n_in; (void)out_size; (void)ws_size;
}